// Round 4
// baseline (368.704 us; speedup 1.0000x reference)
//
#include <hip/hip_runtime.h>

typedef unsigned short u16;
typedef short short8 __attribute__((ext_vector_type(8)));
typedef float f32x4 __attribute__((ext_vector_type(4)));

#define AS1C const __attribute__((address_space(1))) void*
#define AS3P __attribute__((address_space(3))) void*

// ---------- bf16 helpers ----------
__device__ __forceinline__ u16 f2b(float f) {
  unsigned u = __float_as_uint(f);
  return (u16)((u + 0x7fffu + ((u >> 16) & 1u)) >> 16);   // RNE
}
__device__ __forceinline__ float b2f(u16 h) {
  return __uint_as_float((unsigned)h << 16);
}

// ---------- problem constants ----------
#define BB 8
#define SS 4096
#define DD 256
#define MTOK (BB*SS)          // 32768 tokens

// ---------- workspace offsets (bytes) ----------
#define OFF_WQKVT  ((size_t)0)           // bf16 [1536][256]
#define OFF_WOT    ((size_t)786432)      // bf16 [256][512]
#define OFF_W1T    ((size_t)1048576)     // bf16 [1024][256]
#define OFF_W2T    ((size_t)1572864)     // bf16 [256][1024]
#define OFF_BQKV   ((size_t)2097152)     // f32  [1536]
#define OFF_XB     ((size_t)2103296)     // bf16 [32768][256]
#define OFF_QKV    ((size_t)18880512)    // bf16 [32768][1536] (V third unused)
#define OFF_YB     ((size_t)52434944)    // bf16 [32768][256]
#define OFF_HB     ((size_t)69212160)    // bf16 [32768][1024]
#define OFF_VT     ((size_t)119543808)   // bf16 [128][256][512]
#define OFF_CTX    ((size_t)153098240)   // bf16 [32768][512]

// ---------------------------------------------------------------------------
__global__ __launch_bounds__(256) void cast_x_kernel(const float* __restrict__ x,
                                                     u16* __restrict__ xb) {
  size_t i = ((size_t)blockIdx.x * 256 + threadIdx.x) * 4;
  float4 v = *(const float4*)(x + i);
  ushort4 o;
  o.x = f2b(v.x); o.y = f2b(v.y); o.z = f2b(v.z); o.w = f2b(v.w);
  *(ushort4*)(xb + i) = o;
}

// ---------------------------------------------------------------------------
__global__ __launch_bounds__(256) void prep_w_kernel(
    const float* __restrict__ Wq, const float* __restrict__ Wk, const float* __restrict__ Wv,
    const float* __restrict__ Wo, const float* __restrict__ W1, const float* __restrict__ W2,
    const float* __restrict__ bq, const float* __restrict__ bk, const float* __restrict__ bv,
    u16* __restrict__ wqkvt, u16* __restrict__ wot, u16* __restrict__ w1t,
    u16* __restrict__ w2t, float* __restrict__ bqkv)
{
  for (int i = blockIdx.x * 256 + threadIdx.x; i < 1050112; i += 1024 * 256) {
    if (i < 393216) {                       // WQKVT [1536][256]
      int n = i >> 8, d = i & 255;
      const float* W = (n < 512) ? Wq : (n < 1024) ? Wk : Wv;
      int nn = n & 511;
      wqkvt[i] = f2b(W[d * 512 + nn]);
    } else if (i < 524288) {                // WOT [256][512]
      int j = i - 393216;
      int dout = j >> 9, hk = j & 511;
      wot[j] = f2b(Wo[hk * 256 + dout]);
    } else if (i < 786432) {                // W1T [1024][256]
      int j = i - 524288;
      int f = j >> 8, d = j & 255;
      w1t[j] = f2b(W1[d * 1024 + f]);
    } else if (i < 1048576) {               // W2T [256][1024]
      int j = i - 786432;
      int d = j >> 10, f = j & 1023;
      w2t[j] = f2b(W2[f * 256 + d]);
    } else {                                // bias concat [1536]
      int n = i - 1048576;
      bqkv[n] = (n < 512) ? bq[n] : (n < 1024) ? bk[n - 512] : bv[n - 1024];
    }
  }
}

// ---------------------------------------------------------------------------
// B-resident streaming GEMM for K=256, occupancy-optimized: 32 KB LDS.
// (unchanged)
__global__ __launch_bounds__(256) void gemm_nres(
    const u16* __restrict__ A, const u16* __restrict__ BT,
    const float* __restrict__ bias, u16* __restrict__ C,
    u16* __restrict__ vt, int N, int vbase, int relu)
{
  __shared__ __align__(16) u16 lds[16384];          // 32 KB
  const int tid = threadIdx.x, lane = tid & 63, wid = tid >> 6;
  const int ln = lane & 15, quad = lane >> 4;
  const int pn = blockIdx.x >> 5;                   // n-panel (64 cols)
  const int mg = blockIdx.x & 31;                   // m-chunk (1024 rows)
  const int wno = (wid >> 1) << 5;                  // 0 / 32
  const int wmo = (wid & 1) << 4;                   // 0 / 16
  const long mbase = (long)mg << 10;
  const int nb = pn << 6;
  const u16* Bp = BT + (size_t)nb * 256;
  const u16* Ap = A + (size_t)mbase * 256;

  // ---- phase 0: stage B panel 64x256 (2048 slots of 16B) ----
#pragma unroll
  for (int p = 0; p < 8; p++) {
    const int s = p * 256 + tid;
    const int row = s >> 5, pc = s & 31;
    const int c = pc ^ (row & 31);
    __builtin_amdgcn_global_load_lds(
        (AS1C)(Bp + (size_t)row * 256 + c * 8), (AS3P)(lds + s * 8), 16, 0, 0);
  }
  __syncthreads();
  short8 breg[2][8];                                // 64 VGPRs
#pragma unroll
  for (int j = 0; j < 2; j++) {
    const int row = wno + j * 16 + ln;
#pragma unroll
    for (int ks = 0; ks < 8; ks++)
      breg[j][ks] = *(const short8*)(lds + row * 256 + (((ks << 2) + quad) ^ (row & 31)) * 8);
  }
  __syncthreads();                                  // B reads done before A overwrites

  // ---- A prologue: iter 0 -> buf 0 (1024 slots = 16 KB) ----
#pragma unroll
  for (int p = 0; p < 4; p++) {
    const int s = p * 256 + tid;
    const int row = s >> 5, pc = s & 31;
    const int c = pc ^ (row & 31);
    __builtin_amdgcn_global_load_lds(
        (AS1C)(Ap + (size_t)row * 256 + c * 8), (AS3P)(lds + s * 8), 16, 0, 0);
  }

  for (int it = 0; it < 32; it++) {
    const int cur = it & 1;
    const u16* Ab = lds + cur * 8192;
    __syncthreads();                                // drains buf-cur loads
    if (it + 1 < 32) {                              // prefetch next 32-row slab
      const u16* An = Ap + (size_t)(it + 1) * 32 * 256;
      u16* Ax = lds + (cur ^ 1) * 8192;
#pragma unroll
      for (int p = 0; p < 4; p++) {
        const int s = p * 256 + tid;
        const int row = s >> 5, pc = s & 31;
        const int c = pc ^ (row & 31);
        __builtin_amdgcn_global_load_lds(
            (AS1C)(An + (size_t)row * 256 + c * 8), (AS3P)(Ax + s * 8), 16, 0, 0);
      }
    }
    f32x4 acc[2];
    acc[0] = (f32x4){0.f, 0.f, 0.f, 0.f};
    acc[1] = (f32x4){0.f, 0.f, 0.f, 0.f};
    const int r0 = wmo + ln;
#pragma unroll
    for (int ks = 0; ks < 8; ks++) {
      const short8 a0 = *(const short8*)(Ab + r0 * 256 + (((ks << 2) + quad) ^ (r0 & 31)) * 8);
      acc[0] = __builtin_amdgcn_mfma_f32_16x16x32_bf16(breg[0][ks], a0, acc[0], 0, 0, 0);
      acc[1] = __builtin_amdgcn_mfma_f32_16x16x32_bf16(breg[1][ks], a0, acc[1], 0, 0, 0);
    }
    // ---- epilogue for this 32-row slab ----
    const long m = mbase + it * 32 + wmo + ln;
    if (nb < vbase) {
#pragma unroll
      for (int j = 0; j < 2; j++) {
        const int n0 = nb + wno + j * 16 + quad * 4;
        f32x4 v = acc[j];
        const float4 b4 = *(const float4*)(bias + n0);
        v[0] += b4.x; v[1] += b4.y; v[2] += b4.z; v[3] += b4.w;
        if (relu) {
#pragma unroll
          for (int r = 0; r < 4; r++) v[r] = fmaxf(v[r], 0.f);
        }
        ushort4 ob;
        ob.x = f2b(v[0]); ob.y = f2b(v[1]); ob.z = f2b(v[2]); ob.w = f2b(v[3]);
        *(ushort4*)(C + (size_t)m * N + n0) = ob;
      }
    } else {
      // V-panel: write transposed to VT[blk=bw*2+h][k][t]
      const int bw = (int)(m >> 9), t = (int)(m & 511);
#pragma unroll
      for (int j = 0; j < 2; j++) {
        const int n0 = nb + wno + j * 16 + quad * 4;
        const int rel = n0 - vbase;
        const int h = rel >> 8, k0 = rel & 255;
        u16* vp = vt + (size_t)(bw * 2 + h) * 131072 + (size_t)k0 * 512 + t;
        const float4 b4 = *(const float4*)(bias + n0);
        vp[0]    = f2b(acc[j][0] + b4.x);
        vp[512]  = f2b(acc[j][1] + b4.y);
        vp[1024] = f2b(acc[j][2] + b4.z);
        vp[1536] = f2b(acc[j][3] + b4.w);
      }
    }
  }
}

// ---------------------------------------------------------------------------
// FUSED attention v5: per-wave private staging pipelines (coalesced), minimal
// barriers. Block = one (b,w,h) x 64 Q-rows. 512 threads = 8 waves.
//   - Q: staged ONCE to LDS (32 KB, XOR-swizzled source, linear dest), 1 barrier.
//   - K: per-wave-disjoint 64-row stripes -> each wave runs a PRIVATE pipeline:
//     coalesced reg loads (64 B/row, issue-early) -> ds_write into its own 4 KB
//     swizzled buffer (write-late) -> ds_read frags. Same-wave DS ops are
//     in-order => ZERO barriers across all 8 k-steps (v2 had 8 full-block
//     2300-load convoys here).
//   - softmax: exact, 2 barriers (unchanged).
//   - PV: P per-chunk via double-buffered 2x9 KB slabs, ONE light barrier per
//     chunk (v2 had 2, each gating a cooperative V-convoy). V flows through the
//     same per-wave private pipeline (no barrier, no cross-wave vmcnt gating).
// LDS 69632 B -> 2 blocks/CU. Peak regs ~120 (<=128, launch_bounds(512,4)).
__global__ __launch_bounds__(512, 4) void attn_fused(const u16* __restrict__ qkv,
                                                     const u16* __restrict__ vt,
                                                     u16* __restrict__ ctx)
{
  __shared__ __align__(16) u16 lds[34816];          // 69632 B
  const int tid = threadIdx.x, lane = tid & 63, wid = tid >> 6;
  const int ln = lane & 15, quad = lane >> 4;
  const int bat = blockIdx.x & 127, mt = blockIdx.x >> 7;
  const int bw = bat >> 1, h = bat & 1;
  const u16* Qb = qkv + (size_t)bw * 786432 + (size_t)h * 256 + (size_t)(mt * 64) * 1536;
  const u16* Kb = qkv + (size_t)bw * 786432 + 512 + (size_t)h * 256;
  const u16* Vb = vt + (size_t)bat * 131072;        // [256][512]
  const int wn = wid * 64;
  const int wno = wid * 32;
  u16* Qs = lds;                                    // [0,32768B): 2048 16B slots
  u16* kbuf = lds + 16384 + wid * 2048;             // [32768,65536B): 8 x 4KB
  float* red1 = (float*)(lds + 32768);              // [65536,69632B)
  float* red2 = red1 + 512;
  u16* Pb0 = lds;                                   // phase2: [0,9216B) 64x72
  u16* Pb1 = lds + 4608;                            // phase2: [9216,18432B)
  u16* vbuf = lds + 16384 + wid * 2048;             // phase2: per-wave 4KB

  // ---- stage Q once: dest linear, source col-XOR-swizzled (conflict-free reads)
#pragma unroll
  for (int p = 0; p < 4; p++) {
    const int s = p * 512 + tid;
    const int r = s >> 5, cc = s & 31;
    const int c = cc ^ (r & 31);
    __builtin_amdgcn_global_load_lds(
        (AS1C)(Qb + (size_t)r * 1536 + c * 8), (AS3P)(Qs + s * 8), 16, 0, 0);
  }

  // ---- K prologue: tile 0 -> regs (coalesced: 64 B of own row per lane) ----
  const u16* Kg = Kb + (size_t)(wn + lane) * 1536;
  const int ksw = (lane >> 2) & 3;          // write-side slot swizzle (row=lane)
  const int krd = (ln >> 2) & 3;            // read-side slot swizzle
  short8 kx[4];
#pragma unroll
  for (int c = 0; c < 4; c++) kx[c] = *(const short8*)(Kg + c * 8);

  __syncthreads();                          // Q resident (drains K loads too)

#pragma unroll
  for (int c = 0; c < 4; c++)
    *(short8*)(kbuf + (lane * 4 + (c ^ ksw)) * 8) = kx[c];

  // ---- phase 1: S = Q K^T, per-wave pipeline, NO barriers ----
  f32x4 acc[4][4];
#pragma unroll
  for (int i = 0; i < 4; i++)
#pragma unroll
    for (int j = 0; j < 4; j++) acc[i][j] = (f32x4){0.f, 0.f, 0.f, 0.f};

  for (int ki = 0; ki < 8; ki++) {
    if (ki < 7) {                           // issue next K tile early (T14)
#pragma unroll
      for (int c = 0; c < 4; c++)
        kx[c] = *(const short8*)(Kg + (ki + 1) * 32 + c * 8);
    }
    short8 a[4], b[4];
#pragma unroll
    for (int i = 0; i < 4; i++) {
      const int r = i * 16 + ln;
      a[i] = *(const short8*)(Qs + (r * 32 + ((ki * 4 + quad) ^ (r & 31))) * 8);
    }
#pragma unroll
    for (int j = 0; j < 4; j++)
      b[j] = *(const short8*)(kbuf + ((j * 16 + ln) * 4 + (quad ^ krd)) * 8);
    __builtin_amdgcn_s_setprio(1);
#pragma unroll
    for (int i = 0; i < 4; i++)
#pragma unroll
      for (int j = 0; j < 4; j++)
        acc[i][j] = __builtin_amdgcn_mfma_f32_16x16x32_bf16(b[j], a[i], acc[i][j], 0, 0, 0);
    __builtin_amdgcn_s_setprio(0);
    if (ki < 7) {                           // write-late; same-wave DS in-order
#pragma unroll
      for (int c = 0; c < 4; c++)
        *(short8*)(kbuf + (lane * 4 + (c ^ ksw)) * 8) = kx[c];
    }
  }

  // ---- exact softmax over the 512-wide rows ----
  float rowmax[4], rowsum[4];
#pragma unroll
  for (int i = 0; i < 4; i++) {
    float m = -1e30f;
#pragma unroll
    for (int j = 0; j < 4; j++)
#pragma unroll
      for (int r = 0; r < 4; r++) m = fmaxf(m, acc[i][j][r]);
    m = fmaxf(m, __shfl_xor(m, 16));
    m = fmaxf(m, __shfl_xor(m, 32));
    if (quad == 0) red1[wid * 64 + i * 16 + ln] = m;
  }
  __syncthreads();
#pragma unroll
  for (int i = 0; i < 4; i++) {
    float m = -1e30f;
#pragma unroll
    for (int w = 0; w < 8; w++) m = fmaxf(m, red1[w * 64 + i * 16 + ln]);
    rowmax[i] = m;
  }

  // V chunk 0 -> regs, issued early (covered by exp pass + sum reduce)
  const int rv = lane & 31, so = lane >> 5;
  const int vsw = rv & 7;
  const u16* Vg = Vb + (size_t)(wno + rv) * 512;
  short8 vx[4];
#pragma unroll
  for (int p = 0; p < 4; p++) vx[p] = *(const short8*)(Vg + (so + 2 * p) * 8);

#pragma unroll
  for (int i = 0; i < 4; i++) {
    float s = 0.f;
#pragma unroll
    for (int j = 0; j < 4; j++)
#pragma unroll
      for (int r = 0; r < 4; r++) {
        const float e = __expf((acc[i][j][r] - rowmax[i]) * 0.0625f); // 1/sqrt(256)
        acc[i][j][r] = e; s += e;
      }
    s += __shfl_xor(s, 16);
    s += __shfl_xor(s, 32);
    if (quad == 0) red2[wid * 64 + i * 16 + ln] = s;
  }
  __syncthreads();
#pragma unroll
  for (int i = 0; i < 4; i++) {
    float s = 0.f;
#pragma unroll
    for (int w = 0; w < 8; w++) s += red2[w * 64 + i * 16 + ln];
    rowsum[i] = 1.f / s;
  }

  // ---- pack P to bf16 regs (acc dies; pb = 32 VGPRs) ----
  ushort4 pb[4][4];
#pragma unroll
  for (int i = 0; i < 4; i++)
#pragma unroll
    for (int j = 0; j < 4; j++) {
      pb[i][j].x = f2b(acc[i][j][0] * rowsum[i]);
      pb[i][j].y = f2b(acc[i][j][1] * rowsum[i]);
      pb[i][j].z = f2b(acc[i][j][2] * rowsum[i]);
      pb[i][j].w = f2b(acc[i][j][3] * rowsum[i]);
    }

  // write V0 to private vbuf (kbuf region is dead for all waves here)
#pragma unroll
  for (int p = 0; p < 4; p++)
    *(short8*)(vbuf + (rv * 8 + ((so + 2 * p) ^ vsw)) * 8) = vx[p];
  // wave 0 drops chunk 0 into slab 0
  if (wid == 0) {
#pragma unroll
    for (int i = 0; i < 4; i++)
#pragma unroll
      for (int j = 0; j < 4; j++)
        *(ushort4*)(Pb0 + (i * 16 + ln) * 72 + j * 16 + quad * 4) = pb[i][j];
  }
  __syncthreads();                          // Pb0 + all vbufs ready

  // ---- phase 2: O = P V ----
  f32x4 o[4][2];
#pragma unroll
  for (int i = 0; i < 4; i++) {
    o[i][0] = (f32x4){0.f, 0.f, 0.f, 0.f};
    o[i][1] = (f32x4){0.f, 0.f, 0.f, 0.f};
  }

  for (int c = 0; c < 8; c++) {
    if (c < 7) {                            // issue next V tile early
#pragma unroll
      for (int p = 0; p < 4; p++)
        vx[p] = *(const short8*)(Vg + (c + 1) * 64 + (so + 2 * p) * 8);
      if (wid == c + 1) {                   // drop next P chunk into other slab
        u16* Pn = ((c + 1) & 1) ? Pb1 : Pb0;
#pragma unroll
        for (int i = 0; i < 4; i++)
#pragma unroll
          for (int j = 0; j < 4; j++)
            *(ushort4*)(Pn + (i * 16 + ln) * 72 + j * 16 + quad * 4) = pb[i][j];
      }
    }
    const u16* Pc = (c & 1) ? Pb1 : Pb0;
    __builtin_amdgcn_s_setprio(1);
#pragma unroll
    for (int ks = 0; ks < 2; ks++) {
      short8 ap[4];
#pragma unroll
      for (int i = 0; i < 4; i++)
        ap[i] = *(const short8*)(Pc + (i * 16 + ln) * 72 + ks * 32 + quad * 8);
#pragma unroll
      for (int j = 0; j < 2; j++) {
        const int rr = j * 16 + ln;
        const short8 bv = *(const short8*)(vbuf + (rr * 8 + ((ks * 4 + quad) ^ (ln & 7))) * 8);
#pragma unroll
        for (int i = 0; i < 4; i++)
          o[i][j] = __builtin_amdgcn_mfma_f32_16x16x32_bf16(bv, ap[i], o[i][j], 0, 0, 0);
      }
    }
    __builtin_amdgcn_s_setprio(0);
    if (c < 7) {                            // write-late V into private buf
#pragma unroll
      for (int p = 0; p < 4; p++)
        *(short8*)(vbuf + (rv * 8 + ((so + 2 * p) ^ vsw)) * 8) = vx[p];
      __syncthreads();                      // slab handoff (light: no staging drain)
    }
  }

  // ---- epilogue: write CTX rows [bw*512+mt*64 .. +64), cols h*256+wno+.. ----
  const size_t tokr0 = (size_t)bw * 512 + mt * 64;
#pragma unroll
  for (int i = 0; i < 4; i++) {
    const size_t row = tokr0 + i * 16 + ln;
#pragma unroll
    for (int j = 0; j < 2; j++) {
      const int col = h * 256 + wno + j * 16 + quad * 4;
      ushort4 ob;
      ob.x = f2b(o[i][j][0]); ob.y = f2b(o[i][j][1]);
      ob.z = f2b(o[i][j][2]); ob.w = f2b(o[i][j][3]);
      *(ushort4*)(ctx + row * 512 + col) = ob;
    }
  }
}

// ---------------------------------------------------------------------------
// GEMM (N=256) with FUSED residual(bf16) + LayerNorm epilogue.
// (dbuf single-barrier staging, unchanged from r3)
__global__ __launch_bounds__(256) void gemm_ln(
    const u16* __restrict__ A, const u16* __restrict__ BT,
    const float* __restrict__ bias, const u16* __restrict__ residb,
    const float* __restrict__ g, const float* __restrict__ beta,
    float* __restrict__ yout, u16* __restrict__ ybout, int K)
{
  __shared__ __align__(16) u16 As[2][2048];   // 2 x 64x32
  __shared__ __align__(16) u16 Bs[2][8192];   // 2 x 256x32
  __shared__ float redS[4][64], redQ[4][64];
  const int tid = threadIdx.x, lane = tid & 63, wid = tid >> 6;
  const int ln = lane & 15, quad = lane >> 4;
  const long bm = (long)blockIdx.x * 64;
  const int wn = wid * 64;
  const u16* Ab = A + (size_t)bm * K;
  const int nk = K >> 5;

  f32x4 acc[4][4];
#pragma unroll
  for (int i = 0; i < 4; i++)
#pragma unroll
    for (int j = 0; j < 4; j++) acc[i][j] = (f32x4){0.f, 0.f, 0.f, 0.f};

  // prologue: stage kt=0 -> buf 0
  {
    const int row = tid >> 2, c = tid & 3;
    __builtin_amdgcn_global_load_lds(
        (AS1C)(Ab + (size_t)row * K + c * 8), (AS3P)(&As[0][0] + tid * 8), 16, 0, 0);
#pragma unroll
    for (int p = 0; p < 4; p++) {
      const int s = p * 256 + tid;
      const int br = s >> 2, bc = s & 3;
      __builtin_amdgcn_global_load_lds(
          (AS1C)(BT + (size_t)br * K + bc * 8), (AS3P)(&Bs[0][0] + s * 8), 16, 0, 0);
    }
  }

  for (int kti = 0; kti < nk; kti++) {
    const int cur = kti & 1;
    __syncthreads();                        // buf-cur arrived; prev reads done
    if (kti + 1 < nk) {                     // prefetch kt+32 -> other buf
      const int kt = (kti + 1) * 32, nxt = cur ^ 1;
      const int row = tid >> 2, c = tid & 3;
      __builtin_amdgcn_global_load_lds(
          (AS1C)(Ab + (size_t)row * K + kt + c * 8), (AS3P)(&As[nxt][0] + tid * 8), 16, 0, 0);
#pragma unroll
      for (int p = 0; p < 4; p++) {
        const int s = p * 256 + tid;
        const int br = s >> 2, bc = s & 3;
        __builtin_amdgcn_global_load_lds(
            (AS1C)(BT + (size_t)br * K + kt + bc * 8), (AS3P)(&Bs[nxt][0] + s * 8), 16, 0, 0);
      }
    }
    short8 a[4], b[4];
#pragma unroll
    for (int i = 0; i < 4; i++) a[i] = *(const short8*)(&As[cur][0] + (i * 16 + ln) * 32 + quad * 8);
#pragma unroll
    for (int j = 0; j < 4; j++) b[j] = *(const short8*)(&Bs[cur][0] + (wn + j * 16 + ln) * 32 + quad * 8);
    __builtin_amdgcn_s_setprio(1);
#pragma unroll
    for (int i = 0; i < 4; i++)
#pragma unroll
      for (int j = 0; j < 4; j++)
        acc[i][j] = __builtin_amdgcn_mfma_f32_16x16x32_bf16(b[j], a[i], acc[i][j], 0, 0, 0);
    __builtin_amdgcn_s_setprio(0);
  }

  // ---- epilogue: v = acc + bias + resid; LayerNorm over the 256-row ----
#pragma unroll
  for (int i = 0; i < 4; i++) {
    const long gm = bm + i * 16 + ln;
    float s = 0.f, q = 0.f;
#pragma unroll
    for (int j = 0; j < 4; j++) {
      const int n0 = wn + j * 16 + quad * 4;
      const float4 b4 = *(const float4*)(bias + n0);
      const ushort4 r4 = *(const ushort4*)(residb + (size_t)gm * 256 + n0);
      acc[i][j][0] += b4.x + b2f(r4.x);
      acc[i][j][1] += b4.y + b2f(r4.y);
      acc[i][j][2] += b4.z + b2f(r4.z);
      acc[i][j][3] += b4.w + b2f(r4.w);
#pragma unroll
      for (int r = 0; r < 4; r++) { s += acc[i][j][r]; q += acc[i][j][r] * acc[i][j][r]; }
    }
    s += __shfl_xor(s, 16); s += __shfl_xor(s, 32);
    q += __shfl_xor(q, 16); q += __shfl_xor(q, 32);
    if (quad == 0) { redS[wid][i * 16 + ln] = s; redQ[wid][i * 16 + ln] = q; }
  }
  __syncthreads();
#pragma unroll
  for (int i = 0; i < 4; i++) {
    const long gm = bm + i * 16 + ln;
    float s = 0.f, q = 0.f;
#pragma unroll
    for (int w = 0; w < 4; w++) { s += redS[w][i * 16 + ln]; q += redQ[w][i * 16 + ln]; }
    const float mu = s * (1.f / 256.f);
    const float inv = rsqrtf(q * (1.f / 256.f) - mu * mu + 1e-3f);
#pragma unroll
    for (int j = 0; j < 4; j++) {
      const int n0 = wn + j * 16 + quad * 4;
      const float4 gg = *(const float4*)(g + n0);
      const float4 bb = *(const float4*)(beta + n0);
      float o0 = (acc[i][j][0] - mu) * inv * gg.x + bb.x;
      float o1 = (acc[i][j][1] - mu) * inv * gg.y + bb.y;
      float o2 = (acc[i][j][2] - mu) * inv * gg.z + bb.z;
      float o3 = (acc[i][j][3] - mu) * inv * gg.w + bb.w;
      const size_t off = (size_t)gm * 256 + n0;
      if (yout) {
        float4 o4; o4.x = o0; o4.y = o1; o4.z = o2; o4.w = o3;
        *(float4*)(yout + off) = o4;
      }
      if (ybout) {
        ushort4 ob;
        ob.x = f2b(o0); ob.y = f2b(o1); ob.z = f2b(o2); ob.w = f2b(o3);
        *(ushort4*)(ybout + off) = ob;
      }
    }
  }
}

// ---------------------------------------------------------------------------
extern "C" void kernel_launch(void* const* d_in, const int* in_sizes, int n_in,
                              void* d_out, int out_size, void* d_ws, size_t ws_size,
                              hipStream_t stream) {
  (void)in_sizes; (void)n_in; (void)out_size; (void)ws_size;
  const float* x    = (const float*)d_in[0];
  const float* Wq   = (const float*)d_in[1];
  const float* bq   = (const float*)d_in[2];
  const float* Wk   = (const float*)d_in[3];
  const float* bk   = (const float*)d_in[4];
  const float* Wv   = (const float*)d_in[5];
  const float* bv   = (const float*)d_in[6];
  const float* Wo   = (const float*)d_in[7];
  const float* bo   = (const float*)d_in[8];
  const float* ln1g = (const float*)d_in[9];
  const float* ln1b = (const float*)d_in[10];
  const float* W1   = (const float*)d_in[11];
  const float* b1   = (const float*)d_in[12];
  const float* W2   = (const float*)d_in[13];
  const float* b2   = (const float*)d_in[14];
  const float* ln2g = (const float*)d_in[15];
  const float* ln2b = (const float*)d_in[16];
  float* out = (float*)d_out;

  char* ws = (char*)d_ws;
  u16*   WQKVT = (u16*)(ws + OFF_WQKVT);
  u16*   WOT   = (u16*)(ws + OFF_WOT);
  u16*   W1T   = (u16*)(ws + OFF_W1T);
  u16*   W2T   = (u16*)(ws + OFF_W2T);
  float* BQKV  = (float*)(ws + OFF_BQKV);
  u16*   XB    = (u16*)(ws + OFF_XB);
  u16*   QKV   = (u16*)(ws + OFF_QKV);
  u16*   YB    = (u16*)(ws + OFF_YB);
  u16*   HB    = (u16*)(ws + OFF_HB);
  u16*   VT    = (u16*)(ws + OFF_VT);
  u16*   CTX   = (u16*)(ws + OFF_CTX);

  cast_x_kernel<<<8192, 256, 0, stream>>>(x, XB);
  prep_w_kernel<<<1024, 256, 0, stream>>>(Wq, Wk, Wv, Wo, W1, W2, bq, bk, bv,
                                          WQKVT, WOT, W1T, W2T, BQKV);
  // QKV projection (B-resident, 32 KB LDS): Q,K -> QKV; V -> VT (fused T)
  gemm_nres<<<768, 256, 0, stream>>>(XB, WQKVT, BQKV, QKV, VT, 1536, 1024, 0);
  // Fused attention v5: per-wave private staging pipelines, minimal barriers
  attn_fused<<<1024, 512, 0, stream>>>(QKV, VT, CTX);
  // attn-out projection + residual(XB) + LN1 -> YB (bf16)
  gemm_ln<<<512, 256, 0, stream>>>(CTX, WOT, bo, XB, ln1g, ln1b, nullptr, YB, 512);
  // FF1 + ReLU (B-resident): [32768,256] x [256,1024]
  gemm_nres<<<512, 256, 0, stream>>>(YB, W1T, b1, HB, nullptr, 1024, 1 << 30, 1);
  // FF2 + residual(YB) + LN2 -> out (f32)
  gemm_ln<<<512, 256, 0, stream>>>(HB, W2T, b2, YB, ln2g, ln2b, out, nullptr, 1024);
}

// Round 6
// 333.422 us; speedup vs baseline: 1.1058x; 1.1058x over previous
//
#include <hip/hip_runtime.h>

typedef unsigned short u16;
typedef short short8 __attribute__((ext_vector_type(8)));
typedef float f32x4 __attribute__((ext_vector_type(4)));

#define AS1C const __attribute__((address_space(1))) void*
#define AS3P __attribute__((address_space(3))) void*

// ---------- bf16 helpers ----------
__device__ __forceinline__ u16 f2b(float f) {
  unsigned u = __float_as_uint(f);
  return (u16)((u + 0x7fffu + ((u >> 16) & 1u)) >> 16);   // RNE
}
__device__ __forceinline__ float b2f(u16 h) {
  return __uint_as_float((unsigned)h << 16);
}

// ---------- problem constants ----------
#define BB 8
#define SS 4096
#define DD 256
#define MTOK (BB*SS)          // 32768 tokens

// ---------- workspace offsets (bytes) ----------
#define OFF_WQKVT  ((size_t)0)           // bf16 [1536][256]
#define OFF_WOT    ((size_t)786432)      // bf16 [256][512]
#define OFF_W1T    ((size_t)1048576)     // bf16 [1024][256]
#define OFF_W2T    ((size_t)1572864)     // bf16 [256][1024]
#define OFF_BQKV   ((size_t)2097152)     // f32  [1536]
#define OFF_XB     ((size_t)2103296)     // bf16 [32768][256]
#define OFF_QKV    ((size_t)18880512)    // bf16 [32768][1536] (V third unused)
#define OFF_YB     ((size_t)52434944)    // bf16 [32768][256]
#define OFF_HB     ((size_t)69212160)    // bf16 [32768][1024]
#define OFF_VT     ((size_t)119543808)   // bf16 [128][256][512]
#define OFF_CTX    ((size_t)153098240)   // bf16 [32768][512]

// ---------------------------------------------------------------------------
__global__ __launch_bounds__(256) void cast_x_kernel(const float* __restrict__ x,
                                                     u16* __restrict__ xb) {
  size_t i = ((size_t)blockIdx.x * 256 + threadIdx.x) * 4;
  float4 v = *(const float4*)(x + i);
  ushort4 o;
  o.x = f2b(v.x); o.y = f2b(v.y); o.z = f2b(v.z); o.w = f2b(v.w);
  *(ushort4*)(xb + i) = o;
}

// ---------------------------------------------------------------------------
__global__ __launch_bounds__(256) void prep_w_kernel(
    const float* __restrict__ Wq, const float* __restrict__ Wk, const float* __restrict__ Wv,
    const float* __restrict__ Wo, const float* __restrict__ W1, const float* __restrict__ W2,
    const float* __restrict__ bq, const float* __restrict__ bk, const float* __restrict__ bv,
    u16* __restrict__ wqkvt, u16* __restrict__ wot, u16* __restrict__ w1t,
    u16* __restrict__ w2t, float* __restrict__ bqkv)
{
  for (int i = blockIdx.x * 256 + threadIdx.x; i < 1050112; i += 1024 * 256) {
    if (i < 393216) {                       // WQKVT [1536][256]
      int n = i >> 8, d = i & 255;
      const float* W = (n < 512) ? Wq : (n < 1024) ? Wk : Wv;
      int nn = n & 511;
      wqkvt[i] = f2b(W[d * 512 + nn]);
    } else if (i < 524288) {                // WOT [256][512]
      int j = i - 393216;
      int dout = j >> 9, hk = j & 511;
      wot[j] = f2b(Wo[hk * 256 + dout]);
    } else if (i < 786432) {                // W1T [1024][256]
      int j = i - 524288;
      int f = j >> 8, d = j & 255;
      w1t[j] = f2b(W1[d * 1024 + f]);
    } else if (i < 1048576) {               // W2T [256][1024]
      int j = i - 786432;
      int d = j >> 10, f = j & 1023;
      w2t[j] = f2b(W2[f * 256 + d]);
    } else {                                // bias concat [1536]
      int n = i - 1048576;
      bqkv[n] = (n < 512) ? bq[n] : (n < 1024) ? bk[n - 512] : bv[n - 1024];
    }
  }
}

// ---------------------------------------------------------------------------
// B-resident streaming GEMM for K=256, occupancy-optimized: 32 KB LDS.
// (unchanged)
__global__ __launch_bounds__(256) void gemm_nres(
    const u16* __restrict__ A, const u16* __restrict__ BT,
    const float* __restrict__ bias, u16* __restrict__ C,
    u16* __restrict__ vt, int N, int vbase, int relu)
{
  __shared__ __align__(16) u16 lds[16384];          // 32 KB
  const int tid = threadIdx.x, lane = tid & 63, wid = tid >> 6;
  const int ln = lane & 15, quad = lane >> 4;
  const int pn = blockIdx.x >> 5;                   // n-panel (64 cols)
  const int mg = blockIdx.x & 31;                   // m-chunk (1024 rows)
  const int wno = (wid >> 1) << 5;                  // 0 / 32
  const int wmo = (wid & 1) << 4;                   // 0 / 16
  const long mbase = (long)mg << 10;
  const int nb = pn << 6;
  const u16* Bp = BT + (size_t)nb * 256;
  const u16* Ap = A + (size_t)mbase * 256;

  // ---- phase 0: stage B panel 64x256 (2048 slots of 16B) ----
#pragma unroll
  for (int p = 0; p < 8; p++) {
    const int s = p * 256 + tid;
    const int row = s >> 5, pc = s & 31;
    const int c = pc ^ (row & 31);
    __builtin_amdgcn_global_load_lds(
        (AS1C)(Bp + (size_t)row * 256 + c * 8), (AS3P)(lds + s * 8), 16, 0, 0);
  }
  __syncthreads();
  short8 breg[2][8];                                // 64 VGPRs
#pragma unroll
  for (int j = 0; j < 2; j++) {
    const int row = wno + j * 16 + ln;
#pragma unroll
    for (int ks = 0; ks < 8; ks++)
      breg[j][ks] = *(const short8*)(lds + row * 256 + (((ks << 2) + quad) ^ (row & 31)) * 8);
  }
  __syncthreads();                                  // B reads done before A overwrites

  // ---- A prologue: iter 0 -> buf 0 (1024 slots = 16 KB) ----
#pragma unroll
  for (int p = 0; p < 4; p++) {
    const int s = p * 256 + tid;
    const int row = s >> 5, pc = s & 31;
    const int c = pc ^ (row & 31);
    __builtin_amdgcn_global_load_lds(
        (AS1C)(Ap + (size_t)row * 256 + c * 8), (AS3P)(lds + s * 8), 16, 0, 0);
  }

  for (int it = 0; it < 32; it++) {
    const int cur = it & 1;
    const u16* Ab = lds + cur * 8192;
    __syncthreads();                                // drains buf-cur loads
    if (it + 1 < 32) {                              // prefetch next 32-row slab
      const u16* An = Ap + (size_t)(it + 1) * 32 * 256;
      u16* Ax = lds + (cur ^ 1) * 8192;
#pragma unroll
      for (int p = 0; p < 4; p++) {
        const int s = p * 256 + tid;
        const int row = s >> 5, pc = s & 31;
        const int c = pc ^ (row & 31);
        __builtin_amdgcn_global_load_lds(
            (AS1C)(An + (size_t)row * 256 + c * 8), (AS3P)(Ax + s * 8), 16, 0, 0);
      }
    }
    f32x4 acc[2];
    acc[0] = (f32x4){0.f, 0.f, 0.f, 0.f};
    acc[1] = (f32x4){0.f, 0.f, 0.f, 0.f};
    const int r0 = wmo + ln;
#pragma unroll
    for (int ks = 0; ks < 8; ks++) {
      const short8 a0 = *(const short8*)(Ab + r0 * 256 + (((ks << 2) + quad) ^ (r0 & 31)) * 8);
      acc[0] = __builtin_amdgcn_mfma_f32_16x16x32_bf16(breg[0][ks], a0, acc[0], 0, 0, 0);
      acc[1] = __builtin_amdgcn_mfma_f32_16x16x32_bf16(breg[1][ks], a0, acc[1], 0, 0, 0);
    }
    // ---- epilogue for this 32-row slab ----
    const long m = mbase + it * 32 + wmo + ln;
    if (nb < vbase) {
#pragma unroll
      for (int j = 0; j < 2; j++) {
        const int n0 = nb + wno + j * 16 + quad * 4;
        f32x4 v = acc[j];
        const float4 b4 = *(const float4*)(bias + n0);
        v[0] += b4.x; v[1] += b4.y; v[2] += b4.z; v[3] += b4.w;
        if (relu) {
#pragma unroll
          for (int r = 0; r < 4; r++) v[r] = fmaxf(v[r], 0.f);
        }
        ushort4 ob;
        ob.x = f2b(v[0]); ob.y = f2b(v[1]); ob.z = f2b(v[2]); ob.w = f2b(v[3]);
        *(ushort4*)(C + (size_t)m * N + n0) = ob;
      }
    } else {
      // V-panel: write transposed to VT[blk=bw*2+h][k][t]
      const int bw = (int)(m >> 9), t = (int)(m & 511);
#pragma unroll
      for (int j = 0; j < 2; j++) {
        const int n0 = nb + wno + j * 16 + quad * 4;
        const int rel = n0 - vbase;
        const int h = rel >> 8, k0 = rel & 255;
        u16* vp = vt + (size_t)(bw * 2 + h) * 131072 + (size_t)k0 * 512 + t;
        const float4 b4 = *(const float4*)(bias + n0);
        vp[0]    = f2b(acc[j][0] + b4.x);
        vp[512]  = f2b(acc[j][1] + b4.y);
        vp[1024] = f2b(acc[j][2] + b4.z);
        vp[1536] = f2b(acc[j][3] + b4.w);
      }
    }
  }
}

// ---------------------------------------------------------------------------
// FUSED attention v6 = v2 (the 70us round-1 structure) + bank-conflict fix.
// v2's Q/K tiles are 64B rows read as b128 at row*64 + quad*16: a 16-lane
// group hits bank-groups {0,16} only -> 8-way conflict (4.7M counted).
// Fix: XOR the 16B-chunk index with ((row>>1)&3) on the global SOURCE of
// global_load_lds (dest stays linear, rule #21) and the same XOR on the
// ds_read side. New bank pattern: (16*ln + 4*(quad^((ln>>1)&3)))%32 covers
// all 8 bank-groups x2 lanes = 2-way = free. Everything else identical to v2.
__global__ __launch_bounds__(512, 4) void attn_fused(const u16* __restrict__ qkv,
                                                     const u16* __restrict__ vt,
                                                     u16* __restrict__ ctx)
{
  __shared__ __align__(16) u16 lds[38912];          // 77824 B
  const int tid = threadIdx.x, lane = tid & 63, wid = tid >> 6;
  const int ln = lane & 15, quad = lane >> 4;
  const int bat = blockIdx.x & 127, mt = blockIdx.x >> 7;
  const int bw = bat >> 1, h = bat & 1;
  const u16* Qb = qkv + (size_t)bw * 786432 + (size_t)h * 256 + (size_t)(mt * 64) * 1536;
  const u16* Kb = qkv + (size_t)bw * 786432 + 512 + (size_t)h * 256;
  const u16* Vb = vt + (size_t)bat * 131072;        // [256][512]
  const int wn = wid * 64;
  const int qsw = (ln >> 1) & 3;            // read-side chunk swizzle
  float* red1 = (float*)(lds + 36864);
  float* red2 = red1 + 512;

  // ---- phase 1: S = Q K^T, double-buffered ----
  f32x4 acc[4][4];
#pragma unroll
  for (int i = 0; i < 4; i++)
#pragma unroll
    for (int j = 0; j < 4; j++) acc[i][j] = (f32x4){0.f, 0.f, 0.f, 0.f};

  // prologue: tile 0 -> buf 0 (source chunk-XOR-swizzled, dest linear)
  if (tid < 256) {                          // Q tile: 64x32 = 256 slots
    const int row = tid >> 2;
    const int c = (tid & 3) ^ ((row >> 1) & 3);
    __builtin_amdgcn_global_load_lds(
        (AS1C)(Qb + (size_t)row * 1536 + c * 8), (AS3P)(lds + tid * 8), 16, 0, 0);
  }
#pragma unroll
  for (int p = 0; p < 4; p++) {             // K tile: 512x32 = 2048 slots
    const int s = p * 512 + tid;
    const int row = s >> 2;
    const int c = (s & 3) ^ ((row >> 1) & 3);
    __builtin_amdgcn_global_load_lds(
        (AS1C)(Kb + (size_t)row * 1536 + c * 8), (AS3P)(lds + 4096 + s * 8), 16, 0, 0);
  }

  for (int ki = 0; ki < 8; ki++) {
    const int cur = ki & 1;
    __syncthreads();                        // tile ki arrived; prev reads done
    if (ki < 7) {                           // prefetch tile ki+1 -> other buf
      const int kt = (ki + 1) * 32, nxt = cur ^ 1;
      if (tid < 256) {
        const int row = tid >> 2;
        const int c = (tid & 3) ^ ((row >> 1) & 3);
        __builtin_amdgcn_global_load_lds(
            (AS1C)(Qb + (size_t)row * 1536 + kt + c * 8),
            (AS3P)(lds + nxt * 2048 + tid * 8), 16, 0, 0);
      }
#pragma unroll
      for (int p = 0; p < 4; p++) {
        const int s = p * 512 + tid;
        const int row = s >> 2;
        const int c = (s & 3) ^ ((row >> 1) & 3);
        __builtin_amdgcn_global_load_lds(
            (AS1C)(Kb + (size_t)row * 1536 + kt + c * 8),
            (AS3P)(lds + 4096 + nxt * 16384 + s * 8), 16, 0, 0);
      }
    }
    short8 a[4], b[4];
#pragma unroll
    for (int i = 0; i < 4; i++)
      a[i] = *(const short8*)(lds + cur * 2048 + ((i * 16 + ln) * 4 + (quad ^ qsw)) * 8);
#pragma unroll
    for (int j = 0; j < 4; j++)
      b[j] = *(const short8*)(lds + 4096 + cur * 16384 + ((wn + j * 16 + ln) * 4 + (quad ^ qsw)) * 8);
    __builtin_amdgcn_s_setprio(1);
#pragma unroll
    for (int i = 0; i < 4; i++)
#pragma unroll
      for (int j = 0; j < 4; j++)
        acc[i][j] = __builtin_amdgcn_mfma_f32_16x16x32_bf16(b[j], a[i], acc[i][j], 0, 0, 0);
    __builtin_amdgcn_s_setprio(0);
  }

  // ---- exact softmax over the 512-wide rows ----
  float rowmax[4], rowsum[4];
#pragma unroll
  for (int i = 0; i < 4; i++) {
    float m = -1e30f;
#pragma unroll
    for (int j = 0; j < 4; j++)
#pragma unroll
      for (int r = 0; r < 4; r++) m = fmaxf(m, acc[i][j][r]);
    m = fmaxf(m, __shfl_xor(m, 16));
    m = fmaxf(m, __shfl_xor(m, 32));
    if (quad == 0) red1[wid * 64 + i * 16 + ln] = m;
  }
  __syncthreads();                          // red1 ready (phase-1 LDS now dead)

  // issue V chunk 0 early: covered by the exp pass + sum reduction
#pragma unroll
  for (int p = 0; p < 4; p++) {             // V^T chunk: 256 rows x 128 B
    const int s = p * 512 + tid;
    const int row = s >> 3, pc = s & 7;
    const int cc = pc ^ (row & 7);
    __builtin_amdgcn_global_load_lds(
        (AS1C)(Vb + (size_t)row * 512 + cc * 8), (AS3P)(lds + s * 8), 16, 0, 0);
  }

#pragma unroll
  for (int i = 0; i < 4; i++) {
    float m = -1e30f;
#pragma unroll
    for (int w = 0; w < 8; w++) m = fmaxf(m, red1[w * 64 + i * 16 + ln]);
    rowmax[i] = m;
  }
#pragma unroll
  for (int i = 0; i < 4; i++) {
    float s = 0.f;
#pragma unroll
    for (int j = 0; j < 4; j++)
#pragma unroll
      for (int r = 0; r < 4; r++) {
        const float e = __expf((acc[i][j][r] - rowmax[i]) * 0.0625f); // 1/sqrt(256)
        acc[i][j][r] = e; s += e;
      }
    s += __shfl_xor(s, 16);
    s += __shfl_xor(s, 32);
    if (quad == 0) red2[wid * 64 + i * 16 + ln] = s;
  }
  __syncthreads();                          // red2 ready (also drains V0)
#pragma unroll
  for (int i = 0; i < 4; i++) {
    float s = 0.f;
#pragma unroll
    for (int w = 0; w < 8; w++) s += red2[w * 64 + i * 16 + ln];
    rowsum[i] = 1.f / s;
  }

  // ---- pack P to bf16 regs: acc (64 regs) dies here, pb = 32 regs ----
  ushort4 pb[4][4];
#pragma unroll
  for (int i = 0; i < 4; i++)
#pragma unroll
    for (int j = 0; j < 4; j++) {
      pb[i][j].x = f2b(acc[i][j][0] * rowsum[i]);
      pb[i][j].y = f2b(acc[i][j][1] * rowsum[i]);
      pb[i][j].z = f2b(acc[i][j][2] * rowsum[i]);
      pb[i][j].w = f2b(acc[i][j][3] * rowsum[i]);
    }

  // ---- phase 2: O = P V, double-buffered V chunks ----
  u16* Pb = lds + 32768;                    // 64 x 72 bf16 (9216 B)
  const int wno = wid * 32;
  f32x4 o[4][2];
#pragma unroll
  for (int i = 0; i < 4; i++) {
    o[i][0] = (f32x4){0.f, 0.f, 0.f, 0.f};
    o[i][1] = (f32x4){0.f, 0.f, 0.f, 0.f};
  }

  for (int c = 0; c < 8; c++) {
    __syncthreads();                        // (A) V_c arrived; prev Pb/V reads done
    if (wid == c) {                         // owning wave drops its packed P-slice
#pragma unroll
      for (int i = 0; i < 4; i++)
#pragma unroll
        for (int j = 0; j < 4; j++)
          *(ushort4*)(Pb + (i * 16 + ln) * 72 + j * 16 + quad * 4) = pb[i][j];
    }
    __syncthreads();                        // (B) Pbuf ready (cheap: no vmem pending)
    if (c < 7) {                            // prefetch V chunk c+1, covered by MFMAs
      const int nb = (c + 1) & 1;
#pragma unroll
      for (int p = 0; p < 4; p++) {
        const int s = p * 512 + tid;
        const int row = s >> 3, pc = s & 7;
        const int cc = pc ^ (row & 7);
        __builtin_amdgcn_global_load_lds(
            (AS1C)(Vb + (size_t)row * 512 + (c + 1) * 64 + cc * 8),
            (AS3P)(lds + nb * 16384 + s * 8), 16, 0, 0);
      }
    }
    const u16* Vc = lds + (c & 1) * 16384;
    __builtin_amdgcn_s_setprio(1);
#pragma unroll
    for (int ks = 0; ks < 2; ks++) {
      short8 ap[4];
#pragma unroll
      for (int i = 0; i < 4; i++)
        ap[i] = *(const short8*)(Pb + (i * 16 + ln) * 72 + ks * 32 + quad * 8);
#pragma unroll
      for (int j = 0; j < 2; j++) {
        const int kV = wno + j * 16 + ln;
        const short8 bv = *(const short8*)(Vc + kV * 64 + (((ks << 2) + quad) ^ (kV & 7)) * 8);
#pragma unroll
        for (int i = 0; i < 4; i++)
          o[i][j] = __builtin_amdgcn_mfma_f32_16x16x32_bf16(bv, ap[i], o[i][j], 0, 0, 0);
      }
    }
    __builtin_amdgcn_s_setprio(0);
  }

  // ---- epilogue: write CTX rows [bw*512+mt*64 .. +64), cols h*256+wno+.. ----
  const size_t tokr0 = (size_t)bw * 512 + mt * 64;
#pragma unroll
  for (int i = 0; i < 4; i++) {
    const size_t row = tokr0 + i * 16 + ln;
#pragma unroll
    for (int j = 0; j < 2; j++) {
      const int col = h * 256 + wno + j * 16 + quad * 4;
      ushort4 ob;
      ob.x = f2b(o[i][j][0]); ob.y = f2b(o[i][j][1]);
      ob.z = f2b(o[i][j][2]); ob.w = f2b(o[i][j][3]);
      *(ushort4*)(ctx + row * 512 + col) = ob;
    }
  }
}

// ---------------------------------------------------------------------------
// GEMM (N=256) with FUSED residual(bf16) + LayerNorm epilogue.
// dbuf single-barrier staging + the same chunk-XOR bank-conflict fix as attn.
__global__ __launch_bounds__(256) void gemm_ln(
    const u16* __restrict__ A, const u16* __restrict__ BT,
    const float* __restrict__ bias, const u16* __restrict__ residb,
    const float* __restrict__ g, const float* __restrict__ beta,
    float* __restrict__ yout, u16* __restrict__ ybout, int K)
{
  __shared__ __align__(16) u16 As[2][2048];   // 2 x 64x32
  __shared__ __align__(16) u16 Bs[2][8192];   // 2 x 256x32
  __shared__ float redS[4][64], redQ[4][64];
  const int tid = threadIdx.x, lane = tid & 63, wid = tid >> 6;
  const int ln = lane & 15, quad = lane >> 4;
  const int qsw = (ln >> 1) & 3;
  const long bm = (long)blockIdx.x * 64;
  const int wn = wid * 64;
  const u16* Ab = A + (size_t)bm * K;
  const int nk = K >> 5;

  f32x4 acc[4][4];
#pragma unroll
  for (int i = 0; i < 4; i++)
#pragma unroll
    for (int j = 0; j < 4; j++) acc[i][j] = (f32x4){0.f, 0.f, 0.f, 0.f};

  // prologue: stage kt=0 -> buf 0 (source chunk-XOR-swizzled)
  {
    const int row = tid >> 2;
    const int c = (tid & 3) ^ ((row >> 1) & 3);
    __builtin_amdgcn_global_load_lds(
        (AS1C)(Ab + (size_t)row * K + c * 8), (AS3P)(&As[0][0] + tid * 8), 16, 0, 0);
#pragma unroll
    for (int p = 0; p < 4; p++) {
      const int s = p * 256 + tid;
      const int br = s >> 2;
      const int bc = (s & 3) ^ ((br >> 1) & 3);
      __builtin_amdgcn_global_load_lds(
          (AS1C)(BT + (size_t)br * K + bc * 8), (AS3P)(&Bs[0][0] + s * 8), 16, 0, 0);
    }
  }

  for (int kti = 0; kti < nk; kti++) {
    const int cur = kti & 1;
    __syncthreads();                        // buf-cur arrived; prev reads done
    if (kti + 1 < nk) {                     // prefetch kt+32 -> other buf
      const int kt = (kti + 1) * 32, nxt = cur ^ 1;
      const int row = tid >> 2;
      const int c = (tid & 3) ^ ((row >> 1) & 3);
      __builtin_amdgcn_global_load_lds(
          (AS1C)(Ab + (size_t)row * K + kt + c * 8), (AS3P)(&As[nxt][0] + tid * 8), 16, 0, 0);
#pragma unroll
      for (int p = 0; p < 4; p++) {
        const int s = p * 256 + tid;
        const int br = s >> 2;
        const int bc = (s & 3) ^ ((br >> 1) & 3);
        __builtin_amdgcn_global_load_lds(
            (AS1C)(BT + (size_t)br * K + kt + bc * 8), (AS3P)(&Bs[nxt][0] + s * 8), 16, 0, 0);
      }
    }
    short8 a[4], b[4];
#pragma unroll
    for (int i = 0; i < 4; i++)
      a[i] = *(const short8*)(&As[cur][0] + ((i * 16 + ln) * 4 + (quad ^ qsw)) * 8);
#pragma unroll
    for (int j = 0; j < 4; j++)
      b[j] = *(const short8*)(&Bs[cur][0] + ((wn + j * 16 + ln) * 4 + (quad ^ qsw)) * 8);
    __builtin_amdgcn_s_setprio(1);
#pragma unroll
    for (int i = 0; i < 4; i++)
#pragma unroll
      for (int j = 0; j < 4; j++)
        acc[i][j] = __builtin_amdgcn_mfma_f32_16x16x32_bf16(b[j], a[i], acc[i][j], 0, 0, 0);
    __builtin_amdgcn_s_setprio(0);
  }

  // ---- epilogue: v = acc + bias + resid; LayerNorm over the 256-row ----
#pragma unroll
  for (int i = 0; i < 4; i++) {
    const long gm = bm + i * 16 + ln;
    float s = 0.f, q = 0.f;
#pragma unroll
    for (int j = 0; j < 4; j++) {
      const int n0 = wn + j * 16 + quad * 4;
      const float4 b4 = *(const float4*)(bias + n0);
      const ushort4 r4 = *(const ushort4*)(residb + (size_t)gm * 256 + n0);
      acc[i][j][0] += b4.x + b2f(r4.x);
      acc[i][j][1] += b4.y + b2f(r4.y);
      acc[i][j][2] += b4.z + b2f(r4.z);
      acc[i][j][3] += b4.w + b2f(r4.w);
#pragma unroll
      for (int r = 0; r < 4; r++) { s += acc[i][j][r]; q += acc[i][j][r] * acc[i][j][r]; }
    }
    s += __shfl_xor(s, 16); s += __shfl_xor(s, 32);
    q += __shfl_xor(q, 16); q += __shfl_xor(q, 32);
    if (quad == 0) { redS[wid][i * 16 + ln] = s; redQ[wid][i * 16 + ln] = q; }
  }
  __syncthreads();
#pragma unroll
  for (int i = 0; i < 4; i++) {
    const long gm = bm + i * 16 + ln;
    float s = 0.f, q = 0.f;
#pragma unroll
    for (int w = 0; w < 4; w++) { s += redS[w][i * 16 + ln]; q += redQ[w][i * 16 + ln]; }
    const float mu = s * (1.f / 256.f);
    const float inv = rsqrtf(q * (1.f / 256.f) - mu * mu + 1e-3f);
#pragma unroll
    for (int j = 0; j < 4; j++) {
      const int n0 = wn + j * 16 + quad * 4;
      const float4 gg = *(const float4*)(g + n0);
      const float4 bb = *(const float4*)(beta + n0);
      float o0 = (acc[i][j][0] - mu) * inv * gg.x + bb.x;
      float o1 = (acc[i][j][1] - mu) * inv * gg.y + bb.y;
      float o2 = (acc[i][j][2] - mu) * inv * gg.z + bb.z;
      float o3 = (acc[i][j][3] - mu) * inv * gg.w + bb.w;
      const size_t off = (size_t)gm * 256 + n0;
      if (yout) {
        float4 o4; o4.x = o0; o4.y = o1; o4.z = o2; o4.w = o3;
        *(float4*)(yout + off) = o4;
      }
      if (ybout) {
        ushort4 ob;
        ob.x = f2b(o0); ob.y = f2b(o1); ob.z = f2b(o2); ob.w = f2b(o3);
        *(ushort4*)(ybout + off) = ob;
      }
    }
  }
}

// ---------------------------------------------------------------------------
extern "C" void kernel_launch(void* const* d_in, const int* in_sizes, int n_in,
                              void* d_out, int out_size, void* d_ws, size_t ws_size,
                              hipStream_t stream) {
  (void)in_sizes; (void)n_in; (void)out_size; (void)ws_size;
  const float* x    = (const float*)d_in[0];
  const float* Wq   = (const float*)d_in[1];
  const float* bq   = (const float*)d_in[2];
  const float* Wk   = (const float*)d_in[3];
  const float* bk   = (const float*)d_in[4];
  const float* Wv   = (const float*)d_in[5];
  const float* bv   = (const float*)d_in[6];
  const float* Wo   = (const float*)d_in[7];
  const float* bo   = (const float*)d_in[8];
  const float* ln1g = (const float*)d_in[9];
  const float* ln1b = (const float*)d_in[10];
  const float* W1   = (const float*)d_in[11];
  const float* b1   = (const float*)d_in[12];
  const float* W2   = (const float*)d_in[13];
  const float* b2   = (const float*)d_in[14];
  const float* ln2g = (const float*)d_in[15];
  const float* ln2b = (const float*)d_in[16];
  float* out = (float*)d_out;

  char* ws = (char*)d_ws;
  u16*   WQKVT = (u16*)(ws + OFF_WQKVT);
  u16*   WOT   = (u16*)(ws + OFF_WOT);
  u16*   W1T   = (u16*)(ws + OFF_W1T);
  u16*   W2T   = (u16*)(ws + OFF_W2T);
  float* BQKV  = (float*)(ws + OFF_BQKV);
  u16*   XB    = (u16*)(ws + OFF_XB);
  u16*   QKV   = (u16*)(ws + OFF_QKV);
  u16*   YB    = (u16*)(ws + OFF_YB);
  u16*   HB    = (u16*)(ws + OFF_HB);
  u16*   VT    = (u16*)(ws + OFF_VT);
  u16*   CTX   = (u16*)(ws + OFF_CTX);

  cast_x_kernel<<<8192, 256, 0, stream>>>(x, XB);
  prep_w_kernel<<<1024, 256, 0, stream>>>(Wq, Wk, Wv, Wo, W1, W2, bq, bk, bv,
                                          WQKVT, WOT, W1T, W2T, BQKV);
  // QKV projection (B-resident, 32 KB LDS): Q,K -> QKV; V -> VT (fused T)
  gemm_nres<<<768, 256, 0, stream>>>(XB, WQKVT, BQKV, QKV, VT, 1536, 1024, 0);
  // Fused attention v6: v2 structure + staged-tile bank-conflict swizzle
  attn_fused<<<1024, 512, 0, stream>>>(QKV, VT, CTX);
  // attn-out projection + residual(XB) + LN1 -> YB (bf16)
  gemm_ln<<<512, 256, 0, stream>>>(CTX, WOT, bo, XB, ln1g, ln1b, nullptr, YB, 512);
  // FF1 + ReLU (B-resident): [32768,256] x [256,1024]
  gemm_nres<<<512, 256, 0, stream>>>(YB, W1T, b1, HB, nullptr, 1024, 1 << 30, 1);
  // FF2 + residual(YB) + LN2 -> out (f32)
  gemm_ln<<<512, 256, 0, stream>>>(HB, W2T, b2, YB, ln2g, ln2b, out, nullptr, 1024);
}

// Round 7
// 319.349 us; speedup vs baseline: 1.1545x; 1.0441x over previous
//
#include <hip/hip_runtime.h>

typedef unsigned short u16;
typedef short short8 __attribute__((ext_vector_type(8)));
typedef float f32x4 __attribute__((ext_vector_type(4)));

#define AS1C const __attribute__((address_space(1))) void*
#define AS3P __attribute__((address_space(3))) void*
#define VMW(n) asm volatile("s_waitcnt vmcnt(" #n ")" ::: "memory")
#define SCHEDB() __builtin_amdgcn_sched_barrier(0)

// ---------- bf16 helpers ----------
__device__ __forceinline__ u16 f2b(float f) {
  unsigned u = __float_as_uint(f);
  return (u16)((u + 0x7fffu + ((u >> 16) & 1u)) >> 16);   // RNE
}
__device__ __forceinline__ float b2f(u16 h) {
  return __uint_as_float((unsigned)h << 16);
}

// ---------- problem constants ----------
#define BB 8
#define SS 4096
#define DD 256
#define MTOK (BB*SS)          // 32768 tokens

// ---------- workspace offsets (bytes) ----------
#define OFF_WQKVT  ((size_t)0)           // bf16 [1536][256]
#define OFF_WOT    ((size_t)786432)      // bf16 [256][512]
#define OFF_W1T    ((size_t)1048576)     // bf16 [1024][256]
#define OFF_W2T    ((size_t)1572864)     // bf16 [256][1024]
#define OFF_BQKV   ((size_t)2097152)     // f32  [1536]
#define OFF_XB     ((size_t)2103296)     // bf16 [32768][256]
#define OFF_QKV    ((size_t)18880512)    // bf16 [32768][1536] (V third unused)
#define OFF_YB     ((size_t)52434944)    // bf16 [32768][256]
#define OFF_HB     ((size_t)69212160)    // bf16 [32768][1024]
#define OFF_VT     ((size_t)119543808)   // bf16 [128][256][512]
#define OFF_CTX    ((size_t)153098240)   // bf16 [32768][512]

// ---------------------------------------------------------------------------
__global__ __launch_bounds__(256) void cast_x_kernel(const float* __restrict__ x,
                                                     u16* __restrict__ xb) {
  size_t i = ((size_t)blockIdx.x * 256 + threadIdx.x) * 4;
  float4 v = *(const float4*)(x + i);
  ushort4 o;
  o.x = f2b(v.x); o.y = f2b(v.y); o.z = f2b(v.z); o.w = f2b(v.w);
  *(ushort4*)(xb + i) = o;
}

// ---------------------------------------------------------------------------
__global__ __launch_bounds__(256) void prep_w_kernel(
    const float* __restrict__ Wq, const float* __restrict__ Wk, const float* __restrict__ Wv,
    const float* __restrict__ Wo, const float* __restrict__ W1, const float* __restrict__ W2,
    const float* __restrict__ bq, const float* __restrict__ bk, const float* __restrict__ bv,
    u16* __restrict__ wqkvt, u16* __restrict__ wot, u16* __restrict__ w1t,
    u16* __restrict__ w2t, float* __restrict__ bqkv)
{
  for (int i = blockIdx.x * 256 + threadIdx.x; i < 1050112; i += 1024 * 256) {
    if (i < 393216) {                       // WQKVT [1536][256]
      int n = i >> 8, d = i & 255;
      const float* W = (n < 512) ? Wq : (n < 1024) ? Wk : Wv;
      int nn = n & 511;
      wqkvt[i] = f2b(W[d * 512 + nn]);
    } else if (i < 524288) {                // WOT [256][512]
      int j = i - 393216;
      int dout = j >> 9, hk = j & 511;
      wot[j] = f2b(Wo[hk * 256 + dout]);
    } else if (i < 786432) {                // W1T [1024][256]
      int j = i - 524288;
      int f = j >> 8, d = j & 255;
      w1t[j] = f2b(W1[d * 1024 + f]);
    } else if (i < 1048576) {               // W2T [256][1024]
      int j = i - 786432;
      int d = j >> 10, f = j & 1023;
      w2t[j] = f2b(W2[f * 256 + d]);
    } else {                                // bias concat [1536]
      int n = i - 1048576;
      bqkv[n] = (n < 512) ? bq[n] : (n < 1024) ? bk[n - 512] : bv[n - 1024];
    }
  }
}

// ---------------------------------------------------------------------------
// B-resident streaming GEMM, v2: 3-deep A-slab ring + counted vmcnt + ONE raw
// barrier per slab (T3/T4). Loads stay in flight across barriers (never
// vmcnt(0) in the loop). Slab it+2 issued AFTER the MFMA/stores of iter it:
// ring[(it+2)%3] was last read in iter it-1, separated by this iter's barrier.
// vmcnt FIFO audit (per-thread): 4 loads/slab; 2 stores (C) or 8 (V) per iter;
// bias hoisted pre-loop. it=0: [slab0 4][slab1 4] -> VMW(4). steady:
// [slab it 4][stores it-1][slab it+1 4] -> VMW(6) C-path / VMW(12) V-path.
// it=31: VMW(0) (one-time full drain). LDS 48KB -> 3 blocks/CU = grid fit.
__global__ __launch_bounds__(256) void gemm_nres(
    const u16* __restrict__ A, const u16* __restrict__ BT,
    const float* __restrict__ bias, u16* __restrict__ C,
    u16* __restrict__ vt, int N, int vbase, int relu)
{
  __shared__ __align__(16) u16 lds[24576];          // 48 KB: ring 3 x 16 KB
  const int tid = threadIdx.x, lane = tid & 63, wid = tid >> 6;
  const int ln = lane & 15, quad = lane >> 4;
  const int pn = blockIdx.x >> 5;                   // n-panel (64 cols)
  const int mg = blockIdx.x & 31;                   // m-chunk (1024 rows)
  const int wno = (wid >> 1) << 5;                  // 0 / 32
  const int wmo = (wid & 1) << 4;                   // 0 / 16
  const long mbase = (long)mg << 10;
  const int nb = pn << 6;
  const u16* Bp = BT + (size_t)nb * 256;
  const u16* Ap = A + (size_t)mbase * 256;

  // ---- phase 0: stage B panel 64x256 (2048 slots of 16B) into lds[0..32KB) ----
#pragma unroll
  for (int p = 0; p < 8; p++) {
    const int s = p * 256 + tid;
    const int row = s >> 5, pc = s & 31;
    const int c = pc ^ (row & 31);
    __builtin_amdgcn_global_load_lds(
        (AS1C)(Bp + (size_t)row * 256 + c * 8), (AS3P)(lds + s * 8), 16, 0, 0);
  }
  __syncthreads();
  short8 breg[2][8];                                // 64 VGPRs
#pragma unroll
  for (int j = 0; j < 2; j++) {
    const int row = wno + j * 16 + ln;
#pragma unroll
    for (int ks = 0; ks < 8; ks++)
      breg[j][ks] = *(const short8*)(lds + row * 256 + (((ks << 2) + quad) ^ (row & 31)) * 8);
  }
  // hoist bias (removes mid-loop VMEM from the vmcnt FIFO)
  const float4 b40 = *(const float4*)(bias + nb + wno + quad * 4);
  const float4 b41 = *(const float4*)(bias + nb + wno + 16 + quad * 4);
  __syncthreads();                                  // B reads done before A overwrites

  // ---- A prologue: slabs 0,1 -> ring 0,1 (4 loads/thread each) ----
#pragma unroll
  for (int sl = 0; sl < 2; sl++) {
    const u16* As = Ap + (size_t)sl * 32 * 256;
#pragma unroll
    for (int p = 0; p < 4; p++) {
      const int s = p * 256 + tid;
      const int row = s >> 5, pc = s & 31;
      const int c = pc ^ (row & 31);
      __builtin_amdgcn_global_load_lds(
          (AS1C)(As + (size_t)row * 256 + c * 8), (AS3P)(lds + sl * 8192 + s * 8), 16, 0, 0);
    }
  }

  for (int it = 0; it < 32; it++) {
    // counted wait: slab-it loads landed; slab it+1 (and prior stores) in flight
    if (it == 0)            VMW(4);
    else if (it == 31)      VMW(0);
    else if (nb < vbase)    VMW(6);
    else                    VMW(12);
    SCHEDB();
    __builtin_amdgcn_s_barrier();
    SCHEDB();
    const u16* Ab = lds + (it % 3) * 8192;
    f32x4 acc[2];
    acc[0] = (f32x4){0.f, 0.f, 0.f, 0.f};
    acc[1] = (f32x4){0.f, 0.f, 0.f, 0.f};
    const int r0 = wmo + ln;
#pragma unroll
    for (int ks = 0; ks < 8; ks++) {
      const short8 a0 = *(const short8*)(Ab + r0 * 256 + (((ks << 2) + quad) ^ (r0 & 31)) * 8);
      acc[0] = __builtin_amdgcn_mfma_f32_16x16x32_bf16(breg[0][ks], a0, acc[0], 0, 0, 0);
      acc[1] = __builtin_amdgcn_mfma_f32_16x16x32_bf16(breg[1][ks], a0, acc[1], 0, 0, 0);
    }
    // ---- epilogue for this 32-row slab ----
    const long m = mbase + it * 32 + wmo + ln;
    if (nb < vbase) {
#pragma unroll
      for (int j = 0; j < 2; j++) {
        const int n0 = nb + wno + j * 16 + quad * 4;
        f32x4 v = acc[j];
        const float4 b4 = j ? b41 : b40;
        v[0] += b4.x; v[1] += b4.y; v[2] += b4.z; v[3] += b4.w;
        if (relu) {
#pragma unroll
          for (int r = 0; r < 4; r++) v[r] = fmaxf(v[r], 0.f);
        }
        ushort4 ob;
        ob.x = f2b(v[0]); ob.y = f2b(v[1]); ob.z = f2b(v[2]); ob.w = f2b(v[3]);
        *(ushort4*)(C + (size_t)m * N + n0) = ob;
      }
    } else {
      // V-panel: write transposed to VT[blk=bw*2+h][k][t]
      const int bw = (int)(m >> 9), t = (int)(m & 511);
#pragma unroll
      for (int j = 0; j < 2; j++) {
        const int n0 = nb + wno + j * 16 + quad * 4;
        const int rel = n0 - vbase;
        const int h = rel >> 8, k0 = rel & 255;
        u16* vp = vt + (size_t)(bw * 2 + h) * 131072 + (size_t)k0 * 512 + t;
        const float4 b4 = j ? b41 : b40;
        vp[0]    = f2b(acc[j][0] + b4.x);
        vp[512]  = f2b(acc[j][1] + b4.y);
        vp[1024] = f2b(acc[j][2] + b4.z);
        vp[1536] = f2b(acc[j][3] + b4.w);
      }
    }
    // ---- issue slab it+2 (ring[(it+2)%3] last read in iter it-1; barrier above separates)
    if (it < 30) {
      const u16* An = Ap + (size_t)(it + 2) * 32 * 256;
      u16* Ax = lds + ((it + 2) % 3) * 8192;
#pragma unroll
      for (int p = 0; p < 4; p++) {
        const int s = p * 256 + tid;
        const int row = s >> 5, pc = s & 31;
        const int c = pc ^ (row & 31);
        __builtin_amdgcn_global_load_lds(
            (AS1C)(An + (size_t)row * 256 + c * 8), (AS3P)(Ax + s * 8), 16, 0, 0);
      }
    }
  }
}

// ---------------------------------------------------------------------------
// FUSED attention v6 (UNCHANGED from round 6: 68.5us, passed).
__global__ __launch_bounds__(512, 4) void attn_fused(const u16* __restrict__ qkv,
                                                     const u16* __restrict__ vt,
                                                     u16* __restrict__ ctx)
{
  __shared__ __align__(16) u16 lds[38912];          // 77824 B
  const int tid = threadIdx.x, lane = tid & 63, wid = tid >> 6;
  const int ln = lane & 15, quad = lane >> 4;
  const int bat = blockIdx.x & 127, mt = blockIdx.x >> 7;
  const int bw = bat >> 1, h = bat & 1;
  const u16* Qb = qkv + (size_t)bw * 786432 + (size_t)h * 256 + (size_t)(mt * 64) * 1536;
  const u16* Kb = qkv + (size_t)bw * 786432 + 512 + (size_t)h * 256;
  const u16* Vb = vt + (size_t)bat * 131072;        // [256][512]
  const int wn = wid * 64;
  const int qsw = (ln >> 1) & 3;            // read-side chunk swizzle
  float* red1 = (float*)(lds + 36864);
  float* red2 = red1 + 512;

  // ---- phase 1: S = Q K^T, double-buffered ----
  f32x4 acc[4][4];
#pragma unroll
  for (int i = 0; i < 4; i++)
#pragma unroll
    for (int j = 0; j < 4; j++) acc[i][j] = (f32x4){0.f, 0.f, 0.f, 0.f};

  // prologue: tile 0 -> buf 0 (source chunk-XOR-swizzled, dest linear)
  if (tid < 256) {                          // Q tile: 64x32 = 256 slots
    const int row = tid >> 2;
    const int c = (tid & 3) ^ ((row >> 1) & 3);
    __builtin_amdgcn_global_load_lds(
        (AS1C)(Qb + (size_t)row * 1536 + c * 8), (AS3P)(lds + tid * 8), 16, 0, 0);
  }
#pragma unroll
  for (int p = 0; p < 4; p++) {             // K tile: 512x32 = 2048 slots
    const int s = p * 512 + tid;
    const int row = s >> 2;
    const int c = (s & 3) ^ ((row >> 1) & 3);
    __builtin_amdgcn_global_load_lds(
        (AS1C)(Kb + (size_t)row * 1536 + c * 8), (AS3P)(lds + 4096 + s * 8), 16, 0, 0);
  }

  for (int ki = 0; ki < 8; ki++) {
    const int cur = ki & 1;
    __syncthreads();                        // tile ki arrived; prev reads done
    if (ki < 7) {                           // prefetch tile ki+1 -> other buf
      const int kt = (ki + 1) * 32, nxt = cur ^ 1;
      if (tid < 256) {
        const int row = tid >> 2;
        const int c = (tid & 3) ^ ((row >> 1) & 3);
        __builtin_amdgcn_global_load_lds(
            (AS1C)(Qb + (size_t)row * 1536 + kt + c * 8),
            (AS3P)(lds + nxt * 2048 + tid * 8), 16, 0, 0);
      }
#pragma unroll
      for (int p = 0; p < 4; p++) {
        const int s = p * 512 + tid;
        const int row = s >> 2;
        const int c = (s & 3) ^ ((row >> 1) & 3);
        __builtin_amdgcn_global_load_lds(
            (AS1C)(Kb + (size_t)row * 1536 + kt + c * 8),
            (AS3P)(lds + 4096 + nxt * 16384 + s * 8), 16, 0, 0);
      }
    }
    short8 a[4], b[4];
#pragma unroll
    for (int i = 0; i < 4; i++)
      a[i] = *(const short8*)(lds + cur * 2048 + ((i * 16 + ln) * 4 + (quad ^ qsw)) * 8);
#pragma unroll
    for (int j = 0; j < 4; j++)
      b[j] = *(const short8*)(lds + 4096 + cur * 16384 + ((wn + j * 16 + ln) * 4 + (quad ^ qsw)) * 8);
    __builtin_amdgcn_s_setprio(1);
#pragma unroll
    for (int i = 0; i < 4; i++)
#pragma unroll
      for (int j = 0; j < 4; j++)
        acc[i][j] = __builtin_amdgcn_mfma_f32_16x16x32_bf16(b[j], a[i], acc[i][j], 0, 0, 0);
    __builtin_amdgcn_s_setprio(0);
  }

  // ---- exact softmax over the 512-wide rows ----
  float rowmax[4], rowsum[4];
#pragma unroll
  for (int i = 0; i < 4; i++) {
    float m = -1e30f;
#pragma unroll
    for (int j = 0; j < 4; j++)
#pragma unroll
      for (int r = 0; r < 4; r++) m = fmaxf(m, acc[i][j][r]);
    m = fmaxf(m, __shfl_xor(m, 16));
    m = fmaxf(m, __shfl_xor(m, 32));
    if (quad == 0) red1[wid * 64 + i * 16 + ln] = m;
  }
  __syncthreads();                          // red1 ready (phase-1 LDS now dead)

  // issue V chunk 0 early: covered by the exp pass + sum reduction
#pragma unroll
  for (int p = 0; p < 4; p++) {             // V^T chunk: 256 rows x 128 B
    const int s = p * 512 + tid;
    const int row = s >> 3, pc = s & 7;
    const int cc = pc ^ (row & 7);
    __builtin_amdgcn_global_load_lds(
        (AS1C)(Vb + (size_t)row * 512 + cc * 8), (AS3P)(lds + s * 8), 16, 0, 0);
  }

#pragma unroll
  for (int i = 0; i < 4; i++) {
    float m = -1e30f;
#pragma unroll
    for (int w = 0; w < 8; w++) m = fmaxf(m, red1[w * 64 + i * 16 + ln]);
    rowmax[i] = m;
  }
#pragma unroll
  for (int i = 0; i < 4; i++) {
    float s = 0.f;
#pragma unroll
    for (int j = 0; j < 4; j++)
#pragma unroll
      for (int r = 0; r < 4; r++) {
        const float e = __expf((acc[i][j][r] - rowmax[i]) * 0.0625f); // 1/sqrt(256)
        acc[i][j][r] = e; s += e;
      }
    s += __shfl_xor(s, 16);
    s += __shfl_xor(s, 32);
    if (quad == 0) red2[wid * 64 + i * 16 + ln] = s;
  }
  __syncthreads();                          // red2 ready (also drains V0)
#pragma unroll
  for (int i = 0; i < 4; i++) {
    float s = 0.f;
#pragma unroll
    for (int w = 0; w < 8; w++) s += red2[w * 64 + i * 16 + ln];
    rowsum[i] = 1.f / s;
  }

  // ---- pack P to bf16 regs: acc (64 regs) dies here, pb = 32 regs ----
  ushort4 pb[4][4];
#pragma unroll
  for (int i = 0; i < 4; i++)
#pragma unroll
    for (int j = 0; j < 4; j++) {
      pb[i][j].x = f2b(acc[i][j][0] * rowsum[i]);
      pb[i][j].y = f2b(acc[i][j][1] * rowsum[i]);
      pb[i][j].z = f2b(acc[i][j][2] * rowsum[i]);
      pb[i][j].w = f2b(acc[i][j][3] * rowsum[i]);
    }

  // ---- phase 2: O = P V, double-buffered V chunks ----
  u16* Pb = lds + 32768;                    // 64 x 72 bf16 (9216 B)
  const int wno = wid * 32;
  f32x4 o[4][2];
#pragma unroll
  for (int i = 0; i < 4; i++) {
    o[i][0] = (f32x4){0.f, 0.f, 0.f, 0.f};
    o[i][1] = (f32x4){0.f, 0.f, 0.f, 0.f};
  }

  for (int c = 0; c < 8; c++) {
    __syncthreads();                        // (A) V_c arrived; prev Pb/V reads done
    if (wid == c) {                         // owning wave drops its packed P-slice
#pragma unroll
      for (int i = 0; i < 4; i++)
#pragma unroll
        for (int j = 0; j < 4; j++)
          *(ushort4*)(Pb + (i * 16 + ln) * 72 + j * 16 + quad * 4) = pb[i][j];
    }
    __syncthreads();                        // (B) Pbuf ready (cheap: no vmem pending)
    if (c < 7) {                            // prefetch V chunk c+1, covered by MFMAs
      const int nb = (c + 1) & 1;
#pragma unroll
      for (int p = 0; p < 4; p++) {
        const int s = p * 512 + tid;
        const int row = s >> 3, pc = s & 7;
        const int cc = pc ^ (row & 7);
        __builtin_amdgcn_global_load_lds(
            (AS1C)(Vb + (size_t)row * 512 + (c + 1) * 64 + cc * 8),
            (AS3P)(lds + nb * 16384 + s * 8), 16, 0, 0);
      }
    }
    const u16* Vc = lds + (c & 1) * 16384;
    __builtin_amdgcn_s_setprio(1);
#pragma unroll
    for (int ks = 0; ks < 2; ks++) {
      short8 ap[4];
#pragma unroll
      for (int i = 0; i < 4; i++)
        ap[i] = *(const short8*)(Pb + (i * 16 + ln) * 72 + ks * 32 + quad * 8);
#pragma unroll
      for (int j = 0; j < 2; j++) {
        const int kV = wno + j * 16 + ln;
        const short8 bv = *(const short8*)(Vc + kV * 64 + (((ks << 2) + quad) ^ (kV & 7)) * 8);
#pragma unroll
        for (int i = 0; i < 4; i++)
          o[i][j] = __builtin_amdgcn_mfma_f32_16x16x32_bf16(bv, ap[i], o[i][j], 0, 0, 0);
      }
    }
    __builtin_amdgcn_s_setprio(0);
  }

  // ---- epilogue: write CTX rows [bw*512+mt*64 .. +64), cols h*256+wno+.. ----
  const size_t tokr0 = (size_t)bw * 512 + mt * 64;
#pragma unroll
  for (int i = 0; i < 4; i++) {
    const size_t row = tokr0 + i * 16 + ln;
#pragma unroll
    for (int j = 0; j < 2; j++) {
      const int col = h * 256 + wno + j * 16 + quad * 4;
      ushort4 ob;
      ob.x = f2b(o[i][j][0]); ob.y = f2b(o[i][j][1]);
      ob.z = f2b(o[i][j][2]); ob.w = f2b(o[i][j][3]);
      *(ushort4*)(ctx + row * 512 + col) = ob;
    }
  }
}

// ---------------------------------------------------------------------------
// GEMM (N=256) + residual + LayerNorm, v3: 3-deep {A,B}-step ring + counted
// vmcnt + ONE raw barrier per k-step. 5 loads/thread/step uniform; no mid-loop
// VMEM besides staging -> VMW(5) steady, VMW(0) last. 62KB LDS -> 2 blocks/CU.
__global__ __launch_bounds__(256) void gemm_ln(
    const u16* __restrict__ A, const u16* __restrict__ BT,
    const float* __restrict__ bias, const u16* __restrict__ residb,
    const float* __restrict__ g, const float* __restrict__ beta,
    float* __restrict__ yout, u16* __restrict__ ybout, int K)
{
  __shared__ __align__(16) u16 ring[3][10240];   // 3 x 20KB: A[0..2048) B[2048..10240)
  __shared__ float redS[4][64], redQ[4][64];
  const int tid = threadIdx.x, lane = tid & 63, wid = tid >> 6;
  const int ln = lane & 15, quad = lane >> 4;
  const int qsw = (ln >> 1) & 3;
  const long bm = (long)blockIdx.x * 64;
  const int wn = wid * 64;
  const u16* Ab = A + (size_t)bm * K;
  const int nk = K >> 5;

  f32x4 acc[4][4];
#pragma unroll
  for (int i = 0; i < 4; i++)
#pragma unroll
    for (int j = 0; j < 4; j++) acc[i][j] = (f32x4){0.f, 0.f, 0.f, 0.f};

  // prologue: stage steps 0,1 -> ring 0,1 (5 loads/thread each)
#pragma unroll
  for (int sl = 0; sl < 2; sl++) {
    const int kt = sl * 32;
    const int row = tid >> 2;
    const int c = (tid & 3) ^ ((row >> 1) & 3);
    __builtin_amdgcn_global_load_lds(
        (AS1C)(Ab + (size_t)row * K + kt + c * 8), (AS3P)(&ring[sl][0] + tid * 8), 16, 0, 0);
#pragma unroll
    for (int p = 0; p < 4; p++) {
      const int s = p * 256 + tid;
      const int br = s >> 2;
      const int bc = (s & 3) ^ ((br >> 1) & 3);
      __builtin_amdgcn_global_load_lds(
          (AS1C)(BT + (size_t)br * K + kt + bc * 8), (AS3P)(&ring[sl][2048] + s * 8), 16, 0, 0);
    }
  }

  for (int kti = 0; kti < nk; kti++) {
    if (kti + 1 < nk) VMW(5); else VMW(0);
    SCHEDB();
    __builtin_amdgcn_s_barrier();
    SCHEDB();
    const u16* Rc = &ring[kti % 3][0];
    short8 a[4], b[4];
#pragma unroll
    for (int i = 0; i < 4; i++)
      a[i] = *(const short8*)(Rc + ((i * 16 + ln) * 4 + (quad ^ qsw)) * 8);
#pragma unroll
    for (int j = 0; j < 4; j++)
      b[j] = *(const short8*)(Rc + 2048 + ((wn + j * 16 + ln) * 4 + (quad ^ qsw)) * 8);
    __builtin_amdgcn_s_setprio(1);
#pragma unroll
    for (int i = 0; i < 4; i++)
#pragma unroll
      for (int j = 0; j < 4; j++)
        acc[i][j] = __builtin_amdgcn_mfma_f32_16x16x32_bf16(b[j], a[i], acc[i][j], 0, 0, 0);
    __builtin_amdgcn_s_setprio(0);
    // issue step kti+2 (ring[(kti+2)%3] last read in iter kti-1; barrier above separates)
    if (kti + 2 < nk) {
      const int kt = (kti + 2) * 32;
      u16* Rn = &ring[(kti + 2) % 3][0];
      const int row = tid >> 2;
      const int c = (tid & 3) ^ ((row >> 1) & 3);
      __builtin_amdgcn_global_load_lds(
          (AS1C)(Ab + (size_t)row * K + kt + c * 8), (AS3P)(Rn + tid * 8), 16, 0, 0);
#pragma unroll
      for (int p = 0; p < 4; p++) {
        const int s = p * 256 + tid;
        const int br = s >> 2;
        const int bc = (s & 3) ^ ((br >> 1) & 3);
        __builtin_amdgcn_global_load_lds(
            (AS1C)(BT + (size_t)br * K + kt + bc * 8), (AS3P)(Rn + 2048 + s * 8), 16, 0, 0);
      }
    }
  }

  // ---- epilogue: v = acc + bias + resid; LayerNorm over the 256-row ----
#pragma unroll
  for (int i = 0; i < 4; i++) {
    const long gm = bm + i * 16 + ln;
    float s = 0.f, q = 0.f;
#pragma unroll
    for (int j = 0; j < 4; j++) {
      const int n0 = wn + j * 16 + quad * 4;
      const float4 b4 = *(const float4*)(bias + n0);
      const ushort4 r4 = *(const ushort4*)(residb + (size_t)gm * 256 + n0);
      acc[i][j][0] += b4.x + b2f(r4.x);
      acc[i][j][1] += b4.y + b2f(r4.y);
      acc[i][j][2] += b4.z + b2f(r4.z);
      acc[i][j][3] += b4.w + b2f(r4.w);
#pragma unroll
      for (int r = 0; r < 4; r++) { s += acc[i][j][r]; q += acc[i][j][r] * acc[i][j][r]; }
    }
    s += __shfl_xor(s, 16); s += __shfl_xor(s, 32);
    q += __shfl_xor(q, 16); q += __shfl_xor(q, 32);
    if (quad == 0) { redS[wid][i * 16 + ln] = s; redQ[wid][i * 16 + ln] = q; }
  }
  __syncthreads();
#pragma unroll
  for (int i = 0; i < 4; i++) {
    const long gm = bm + i * 16 + ln;
    float s = 0.f, q = 0.f;
#pragma unroll
    for (int w = 0; w < 4; w++) { s += redS[w][i * 16 + ln]; q += redQ[w][i * 16 + ln]; }
    const float mu = s * (1.f / 256.f);
    const float inv = rsqrtf(q * (1.f / 256.f) - mu * mu + 1e-3f);
#pragma unroll
    for (int j = 0; j < 4; j++) {
      const int n0 = wn + j * 16 + quad * 4;
      const float4 gg = *(const float4*)(g + n0);
      const float4 bb = *(const float4*)(beta + n0);
      float o0 = (acc[i][j][0] - mu) * inv * gg.x + bb.x;
      float o1 = (acc[i][j][1] - mu) * inv * gg.y + bb.y;
      float o2 = (acc[i][j][2] - mu) * inv * gg.z + bb.z;
      float o3 = (acc[i][j][3] - mu) * inv * gg.w + bb.w;
      const size_t off = (size_t)gm * 256 + n0;
      if (yout) {
        float4 o4; o4.x = o0; o4.y = o1; o4.z = o2; o4.w = o3;
        *(float4*)(yout + off) = o4;
      }
      if (ybout) {
        ushort4 ob;
        ob.x = f2b(o0); ob.y = f2b(o1); ob.z = f2b(o2); ob.w = f2b(o3);
        *(ushort4*)(ybout + off) = ob;
      }
    }
  }
}

// ---------------------------------------------------------------------------
extern "C" void kernel_launch(void* const* d_in, const int* in_sizes, int n_in,
                              void* d_out, int out_size, void* d_ws, size_t ws_size,
                              hipStream_t stream) {
  (void)in_sizes; (void)n_in; (void)out_size; (void)ws_size;
  const float* x    = (const float*)d_in[0];
  const float* Wq   = (const float*)d_in[1];
  const float* bq   = (const float*)d_in[2];
  const float* Wk   = (const float*)d_in[3];
  const float* bk   = (const float*)d_in[4];
  const float* Wv   = (const float*)d_in[5];
  const float* bv   = (const float*)d_in[6];
  const float* Wo   = (const float*)d_in[7];
  const float* bo   = (const float*)d_in[8];
  const float* ln1g = (const float*)d_in[9];
  const float* ln1b = (const float*)d_in[10];
  const float* W1   = (const float*)d_in[11];
  const float* b1   = (const float*)d_in[12];
  const float* W2   = (const float*)d_in[13];
  const float* b2   = (const float*)d_in[14];
  const float* ln2g = (const float*)d_in[15];
  const float* ln2b = (const float*)d_in[16];
  float* out = (float*)d_out;

  char* ws = (char*)d_ws;
  u16*   WQKVT = (u16*)(ws + OFF_WQKVT);
  u16*   WOT   = (u16*)(ws + OFF_WOT);
  u16*   W1T   = (u16*)(ws + OFF_W1T);
  u16*   W2T   = (u16*)(ws + OFF_W2T);
  float* BQKV  = (float*)(ws + OFF_BQKV);
  u16*   XB    = (u16*)(ws + OFF_XB);
  u16*   QKV   = (u16*)(ws + OFF_QKV);
  u16*   YB    = (u16*)(ws + OFF_YB);
  u16*   HB    = (u16*)(ws + OFF_HB);
  u16*   VT    = (u16*)(ws + OFF_VT);
  u16*   CTX   = (u16*)(ws + OFF_CTX);

  cast_x_kernel<<<8192, 256, 0, stream>>>(x, XB);
  prep_w_kernel<<<1024, 256, 0, stream>>>(Wq, Wk, Wv, Wo, W1, W2, bq, bk, bv,
                                          WQKVT, WOT, W1T, W2T, BQKV);
  // QKV projection (ring-3 counted-vmcnt): Q,K -> QKV; V -> VT (fused T)
  gemm_nres<<<768, 256, 0, stream>>>(XB, WQKVT, BQKV, QKV, VT, 1536, 1024, 0);
  // Fused attention v6 (unchanged)
  attn_fused<<<1024, 512, 0, stream>>>(QKV, VT, CTX);
  // attn-out projection + residual(XB) + LN1 -> YB (bf16)
  gemm_ln<<<512, 256, 0, stream>>>(CTX, WOT, bo, XB, ln1g, ln1b, nullptr, YB, 512);
  // FF1 + ReLU (ring-3): [32768,256] x [256,1024]
  gemm_nres<<<512, 256, 0, stream>>>(YB, W1T, b1, HB, nullptr, 1024, 1 << 30, 1);
  // FF2 + residual(YB) + LN2 -> out (f32)
  gemm_ln<<<512, 256, 0, stream>>>(HB, W2T, b2, YB, ln2g, ln2b, out, nullptr, 1024);
}

// Round 8
// 306.122 us; speedup vs baseline: 1.2044x; 1.0432x over previous
//
#include <hip/hip_runtime.h>

typedef unsigned short u16;
typedef short short8 __attribute__((ext_vector_type(8)));
typedef float f32x4 __attribute__((ext_vector_type(4)));

#define AS1C const __attribute__((address_space(1))) void*
#define AS3P __attribute__((address_space(3))) void*
#define VMW(n) asm volatile("s_waitcnt vmcnt(" #n ")" ::: "memory")
#define SCHEDB() __builtin_amdgcn_sched_barrier(0)

// ---------- bf16 helpers ----------
__device__ __forceinline__ u16 f2b(float f) {
  unsigned u = __float_as_uint(f);
  return (u16)((u + 0x7fffu + ((u >> 16) & 1u)) >> 16);   // RNE
}
__device__ __forceinline__ float b2f(u16 h) {
  return __uint_as_float((unsigned)h << 16);
}

// ---------- problem constants ----------
#define BB 8
#define SS 4096
#define DD 256
#define MTOK (BB*SS)          // 32768 tokens

// ---------- workspace offsets (bytes) ----------
#define OFF_WQKVT  ((size_t)0)           // bf16 [1536][256]
#define OFF_WOT    ((size_t)786432)      // bf16 [256][512]
#define OFF_W1T    ((size_t)1048576)     // bf16 [1024][256]
#define OFF_W2T    ((size_t)1572864)     // bf16 [256][1024]
#define OFF_BQKV   ((size_t)2097152)     // f32  [1536]
#define OFF_XB     ((size_t)2103296)     // bf16 [32768][256]
#define OFF_QKV    ((size_t)18880512)    // bf16 [32768][1536] (V third unused)
#define OFF_YB     ((size_t)52434944)    // bf16 [32768][256]
#define OFF_HB     ((size_t)69212160)    // bf16 [32768][1024]
#define OFF_VT     ((size_t)119543808)   // bf16 [128][256][512]
#define OFF_CTX    ((size_t)153098240)   // bf16 [32768][512]

// ---------------------------------------------------------------------------
__global__ __launch_bounds__(256) void cast_x_kernel(const float* __restrict__ x,
                                                     u16* __restrict__ xb) {
  size_t i = ((size_t)blockIdx.x * 256 + threadIdx.x) * 4;
  float4 v = *(const float4*)(x + i);
  ushort4 o;
  o.x = f2b(v.x); o.y = f2b(v.y); o.z = f2b(v.z); o.w = f2b(v.w);
  *(ushort4*)(xb + i) = o;
}

// ---------------------------------------------------------------------------
// prep_w v2: all four weight preps are pure transposes -> 64x64 LDS tile
// transpose (coalesced f32 row reads, padded LDS, coalesced bf16 row writes)
// instead of the old per-element strided gather (1 cache line per 4 bytes).
// Blocks: [0,96) Wq/Wk/Wv 256x512 -> wqkvt; [96,128) Wo 512x256 -> wot;
// [128,192) W1 256x1024 -> w1t; [192,256) W2 1024x256 -> w2t; 256: bias.
__global__ __launch_bounds__(256) void prep_w_kernel(
    const float* __restrict__ Wq, const float* __restrict__ Wk, const float* __restrict__ Wv,
    const float* __restrict__ Wo, const float* __restrict__ W1, const float* __restrict__ W2,
    const float* __restrict__ bq, const float* __restrict__ bk, const float* __restrict__ bv,
    u16* __restrict__ wqkvt, u16* __restrict__ wot, u16* __restrict__ w1t,
    u16* __restrict__ w2t, float* __restrict__ bqkv)
{
  __shared__ float t[64 * 65];
  const int tid = threadIdx.x;
  const int b = blockIdx.x;
  if (b == 256) {                          // bias concat [1536]
    for (int n = tid; n < 1536; n += 256)
      bqkv[n] = (n < 512) ? bq[n] : (n < 1024) ? bk[n - 512] : bv[n - 1024];
    return;
  }
  const float* src; u16* dst; int R, C, tb;
  if (b < 96)       { const int m = b / 32; src = (m == 0) ? Wq : (m == 1) ? Wk : Wv;
                      dst = wqkvt + m * 512 * 256; R = 256; C = 512; tb = b & 31; }
  else if (b < 128) { src = Wo; dst = wot;  R = 512;  C = 256;  tb = b - 96; }
  else if (b < 192) { src = W1; dst = w1t;  R = 256;  C = 1024; tb = b - 128; }
  else              { src = W2; dst = w2t;  R = 1024; C = 256;  tb = b - 192; }
  const int tc = C >> 6;
  const int tr = tb / tc, tcc = tb % tc;
  // load 64x64 f32 tile, coalesced rows
#pragma unroll
  for (int p = 0; p < 16; p++) {
    const int idx = p * 256 + tid, r = idx >> 6, c = idx & 63;
    t[r * 65 + c] = src[(size_t)(tr * 64 + r) * C + tcc * 64 + c];
  }
  __syncthreads();
  // write transposed: dst[C][R], coalesced rows of bf16
#pragma unroll
  for (int p = 0; p < 16; p++) {
    const int idx = p * 256 + tid, c = idx >> 6, r = idx & 63;
    dst[(size_t)(tcc * 64 + c) * R + tr * 64 + r] = f2b(t[r * 65 + c]);
  }
}

// ---------------------------------------------------------------------------
// B-resident streaming GEMM v3: 128-col B-panels (breg[4][8] = 128 VGPR) ->
// A re-read count halves (N/128 panels) and MFMA-per-A-byte doubles (32/iter).
// m-chunk = 512 rows (16 iters) keeps grids at 768/512 (>=2 blocks/CU spread).
// Ring-3 A slabs + counted vmcnt + ONE raw barrier per iter (from r7).
// vmcnt FIFO (per thread): 4 loads/slab; stores/iter: 4 (C) or 16 (V);
// it=0: VMW(4); steady: VMW(8) C / VMW(20) V; it=15: VMW(0).
// LDS 64 KB (B transient) -> 2 blocks/CU; VGPR ~180 -> 2 waves/SIMD.
__global__ __launch_bounds__(256) void gemm_nres(
    const u16* __restrict__ A, const u16* __restrict__ BT,
    const float* __restrict__ bias, u16* __restrict__ C,
    u16* __restrict__ vt, int N, int vbase, int relu)
{
  __shared__ __align__(16) u16 lds[32768];          // 64 KB (B stage / A ring-3)
  const int tid = threadIdx.x, lane = tid & 63, wid = tid >> 6;
  const int ln = lane & 15, quad = lane >> 4;
  const int pn = blockIdx.x >> 6;                   // n-panel (128 cols)
  const int mg = blockIdx.x & 63;                   // m-chunk (512 rows)
  const int wno = (wid >> 1) << 6;                  // 0 / 64
  const int wmo = (wid & 1) << 4;                   // 0 / 16
  const long mbase = (long)mg << 9;
  const int nb = pn << 7;
  const u16* Bp = BT + (size_t)nb * 256;
  const u16* Ap = A + (size_t)mbase * 256;

  // ---- phase 0: stage B panel 128x256 (4096 slots of 16B = 64 KB) ----
#pragma unroll
  for (int p = 0; p < 16; p++) {
    const int s = p * 256 + tid;
    const int row = s >> 5, pc = s & 31;
    const int c = pc ^ (row & 31);
    __builtin_amdgcn_global_load_lds(
        (AS1C)(Bp + (size_t)row * 256 + c * 8), (AS3P)(lds + s * 8), 16, 0, 0);
  }
  __syncthreads();
  short8 breg[4][8];                                // 128 VGPRs
#pragma unroll
  for (int j = 0; j < 4; j++) {
    const int row = wno + j * 16 + ln;
#pragma unroll
    for (int ks = 0; ks < 8; ks++)
      breg[j][ks] = *(const short8*)(lds + row * 256 + (((ks << 2) + quad) ^ (row & 31)) * 8);
  }
  // hoist bias (keeps mid-loop VMEM FIFO = staging + stores only)
  float4 b4h[4];
#pragma unroll
  for (int j = 0; j < 4; j++)
    b4h[j] = *(const float4*)(bias + nb + wno + j * 16 + quad * 4);
  __syncthreads();                                  // B reads done before A overwrites

  // ---- A prologue: slabs 0,1 -> ring 0,1 (4 loads/thread each) ----
#pragma unroll
  for (int sl = 0; sl < 2; sl++) {
    const u16* As = Ap + (size_t)sl * 32 * 256;
#pragma unroll
    for (int p = 0; p < 4; p++) {
      const int s = p * 256 + tid;
      const int row = s >> 5, pc = s & 31;
      const int c = pc ^ (row & 31);
      __builtin_amdgcn_global_load_lds(
          (AS1C)(As + (size_t)row * 256 + c * 8), (AS3P)(lds + sl * 8192 + s * 8), 16, 0, 0);
    }
  }

  for (int it = 0; it < 16; it++) {
    if (it == 0)            VMW(4);
    else if (it == 15)      VMW(0);
    else if (nb < vbase)    VMW(8);
    else                    VMW(20);
    SCHEDB();
    __builtin_amdgcn_s_barrier();
    SCHEDB();
    const u16* Ab = lds + (it % 3) * 8192;
    f32x4 acc[4];
#pragma unroll
    for (int j = 0; j < 4; j++) acc[j] = (f32x4){0.f, 0.f, 0.f, 0.f};
    const int r0 = wmo + ln;
    __builtin_amdgcn_s_setprio(1);
#pragma unroll
    for (int ks = 0; ks < 8; ks++) {
      const short8 a0 = *(const short8*)(Ab + r0 * 256 + (((ks << 2) + quad) ^ (r0 & 31)) * 8);
#pragma unroll
      for (int j = 0; j < 4; j++)
        acc[j] = __builtin_amdgcn_mfma_f32_16x16x32_bf16(breg[j][ks], a0, acc[j], 0, 0, 0);
    }
    __builtin_amdgcn_s_setprio(0);
    // ---- epilogue for this 32-row slab ----
    const long m = mbase + it * 32 + wmo + ln;
    if (nb < vbase) {
#pragma unroll
      for (int j = 0; j < 4; j++) {
        const int n0 = nb + wno + j * 16 + quad * 4;
        f32x4 v = acc[j];
        const float4 b4 = b4h[j];
        v[0] += b4.x; v[1] += b4.y; v[2] += b4.z; v[3] += b4.w;
        if (relu) {
#pragma unroll
          for (int r = 0; r < 4; r++) v[r] = fmaxf(v[r], 0.f);
        }
        ushort4 ob;
        ob.x = f2b(v[0]); ob.y = f2b(v[1]); ob.z = f2b(v[2]); ob.w = f2b(v[3]);
        *(ushort4*)(C + (size_t)m * N + n0) = ob;
      }
    } else {
      // V-panel: write transposed to VT[blk=bw*2+h][k][t]
      const int bw = (int)(m >> 9), t = (int)(m & 511);
#pragma unroll
      for (int j = 0; j < 4; j++) {
        const int n0 = nb + wno + j * 16 + quad * 4;
        const int rel = n0 - vbase;
        const int h = rel >> 8, k0 = rel & 255;
        u16* vp = vt + (size_t)(bw * 2 + h) * 131072 + (size_t)k0 * 512 + t;
        const float4 b4 = b4h[j];
        vp[0]    = f2b(acc[j][0] + b4.x);
        vp[512]  = f2b(acc[j][1] + b4.y);
        vp[1024] = f2b(acc[j][2] + b4.z);
        vp[1536] = f2b(acc[j][3] + b4.w);
      }
    }
    // ---- issue slab it+2 (ring[(it+2)%3] last read iter it-1; barrier separates)
    if (it < 14) {
      const u16* An = Ap + (size_t)(it + 2) * 32 * 256;
      u16* Ax = lds + ((it + 2) % 3) * 8192;
#pragma unroll
      for (int p = 0; p < 4; p++) {
        const int s = p * 256 + tid;
        const int row = s >> 5, pc = s & 31;
        const int c = pc ^ (row & 31);
        __builtin_amdgcn_global_load_lds(
            (AS1C)(An + (size_t)row * 256 + c * 8), (AS3P)(Ax + s * 8), 16, 0, 0);
      }
    }
  }
}

// ---------------------------------------------------------------------------
// FUSED attention v6 (UNCHANGED: ~68us, passed).
__global__ __launch_bounds__(512, 4) void attn_fused(const u16* __restrict__ qkv,
                                                     const u16* __restrict__ vt,
                                                     u16* __restrict__ ctx)
{
  __shared__ __align__(16) u16 lds[38912];          // 77824 B
  const int tid = threadIdx.x, lane = tid & 63, wid = tid >> 6;
  const int ln = lane & 15, quad = lane >> 4;
  const int bat = blockIdx.x & 127, mt = blockIdx.x >> 7;
  const int bw = bat >> 1, h = bat & 1;
  const u16* Qb = qkv + (size_t)bw * 786432 + (size_t)h * 256 + (size_t)(mt * 64) * 1536;
  const u16* Kb = qkv + (size_t)bw * 786432 + 512 + (size_t)h * 256;
  const u16* Vb = vt + (size_t)bat * 131072;        // [256][512]
  const int wn = wid * 64;
  const int qsw = (ln >> 1) & 3;            // read-side chunk swizzle
  float* red1 = (float*)(lds + 36864);
  float* red2 = red1 + 512;

  // ---- phase 1: S = Q K^T, double-buffered ----
  f32x4 acc[4][4];
#pragma unroll
  for (int i = 0; i < 4; i++)
#pragma unroll
    for (int j = 0; j < 4; j++) acc[i][j] = (f32x4){0.f, 0.f, 0.f, 0.f};

  // prologue: tile 0 -> buf 0 (source chunk-XOR-swizzled, dest linear)
  if (tid < 256) {                          // Q tile: 64x32 = 256 slots
    const int row = tid >> 2;
    const int c = (tid & 3) ^ ((row >> 1) & 3);
    __builtin_amdgcn_global_load_lds(
        (AS1C)(Qb + (size_t)row * 1536 + c * 8), (AS3P)(lds + tid * 8), 16, 0, 0);
  }
#pragma unroll
  for (int p = 0; p < 4; p++) {             // K tile: 512x32 = 2048 slots
    const int s = p * 512 + tid;
    const int row = s >> 2;
    const int c = (s & 3) ^ ((row >> 1) & 3);
    __builtin_amdgcn_global_load_lds(
        (AS1C)(Kb + (size_t)row * 1536 + c * 8), (AS3P)(lds + 4096 + s * 8), 16, 0, 0);
  }

  for (int ki = 0; ki < 8; ki++) {
    const int cur = ki & 1;
    __syncthreads();                        // tile ki arrived; prev reads done
    if (ki < 7) {                           // prefetch tile ki+1 -> other buf
      const int kt = (ki + 1) * 32, nxt = cur ^ 1;
      if (tid < 256) {
        const int row = tid >> 2;
        const int c = (tid & 3) ^ ((row >> 1) & 3);
        __builtin_amdgcn_global_load_lds(
            (AS1C)(Qb + (size_t)row * 1536 + kt + c * 8),
            (AS3P)(lds + nxt * 2048 + tid * 8), 16, 0, 0);
      }
#pragma unroll
      for (int p = 0; p < 4; p++) {
        const int s = p * 512 + tid;
        const int row = s >> 2;
        const int c = (s & 3) ^ ((row >> 1) & 3);
        __builtin_amdgcn_global_load_lds(
            (AS1C)(Kb + (size_t)row * 1536 + kt + c * 8),
            (AS3P)(lds + 4096 + nxt * 16384 + s * 8), 16, 0, 0);
      }
    }
    short8 a[4], b[4];
#pragma unroll
    for (int i = 0; i < 4; i++)
      a[i] = *(const short8*)(lds + cur * 2048 + ((i * 16 + ln) * 4 + (quad ^ qsw)) * 8);
#pragma unroll
    for (int j = 0; j < 4; j++)
      b[j] = *(const short8*)(lds + 4096 + cur * 16384 + ((wn + j * 16 + ln) * 4 + (quad ^ qsw)) * 8);
    __builtin_amdgcn_s_setprio(1);
#pragma unroll
    for (int i = 0; i < 4; i++)
#pragma unroll
      for (int j = 0; j < 4; j++)
        acc[i][j] = __builtin_amdgcn_mfma_f32_16x16x32_bf16(b[j], a[i], acc[i][j], 0, 0, 0);
    __builtin_amdgcn_s_setprio(0);
  }

  // ---- exact softmax over the 512-wide rows ----
  float rowmax[4], rowsum[4];
#pragma unroll
  for (int i = 0; i < 4; i++) {
    float m = -1e30f;
#pragma unroll
    for (int j = 0; j < 4; j++)
#pragma unroll
      for (int r = 0; r < 4; r++) m = fmaxf(m, acc[i][j][r]);
    m = fmaxf(m, __shfl_xor(m, 16));
    m = fmaxf(m, __shfl_xor(m, 32));
    if (quad == 0) red1[wid * 64 + i * 16 + ln] = m;
  }
  __syncthreads();                          // red1 ready (phase-1 LDS now dead)

  // issue V chunk 0 early: covered by the exp pass + sum reduction
#pragma unroll
  for (int p = 0; p < 4; p++) {             // V^T chunk: 256 rows x 128 B
    const int s = p * 512 + tid;
    const int row = s >> 3, pc = s & 7;
    const int cc = pc ^ (row & 7);
    __builtin_amdgcn_global_load_lds(
        (AS1C)(Vb + (size_t)row * 512 + cc * 8), (AS3P)(lds + s * 8), 16, 0, 0);
  }

#pragma unroll
  for (int i = 0; i < 4; i++) {
    float m = -1e30f;
#pragma unroll
    for (int w = 0; w < 8; w++) m = fmaxf(m, red1[w * 64 + i * 16 + ln]);
    rowmax[i] = m;
  }
#pragma unroll
  for (int i = 0; i < 4; i++) {
    float s = 0.f;
#pragma unroll
    for (int j = 0; j < 4; j++)
#pragma unroll
      for (int r = 0; r < 4; r++) {
        const float e = __expf((acc[i][j][r] - rowmax[i]) * 0.0625f); // 1/sqrt(256)
        acc[i][j][r] = e; s += e;
      }
    s += __shfl_xor(s, 16);
    s += __shfl_xor(s, 32);
    if (quad == 0) red2[wid * 64 + i * 16 + ln] = s;
  }
  __syncthreads();                          // red2 ready (also drains V0)
#pragma unroll
  for (int i = 0; i < 4; i++) {
    float s = 0.f;
#pragma unroll
    for (int w = 0; w < 8; w++) s += red2[w * 64 + i * 16 + ln];
    rowsum[i] = 1.f / s;
  }

  // ---- pack P to bf16 regs: acc (64 regs) dies here, pb = 32 regs ----
  ushort4 pb[4][4];
#pragma unroll
  for (int i = 0; i < 4; i++)
#pragma unroll
    for (int j = 0; j < 4; j++) {
      pb[i][j].x = f2b(acc[i][j][0] * rowsum[i]);
      pb[i][j].y = f2b(acc[i][j][1] * rowsum[i]);
      pb[i][j].z = f2b(acc[i][j][2] * rowsum[i]);
      pb[i][j].w = f2b(acc[i][j][3] * rowsum[i]);
    }

  // ---- phase 2: O = P V, double-buffered V chunks ----
  u16* Pb = lds + 32768;                    // 64 x 72 bf16 (9216 B)
  const int wno = wid * 32;
  f32x4 o[4][2];
#pragma unroll
  for (int i = 0; i < 4; i++) {
    o[i][0] = (f32x4){0.f, 0.f, 0.f, 0.f};
    o[i][1] = (f32x4){0.f, 0.f, 0.f, 0.f};
  }

  for (int c = 0; c < 8; c++) {
    __syncthreads();                        // (A) V_c arrived; prev Pb/V reads done
    if (wid == c) {                         // owning wave drops its packed P-slice
#pragma unroll
      for (int i = 0; i < 4; i++)
#pragma unroll
        for (int j = 0; j < 4; j++)
          *(ushort4*)(Pb + (i * 16 + ln) * 72 + j * 16 + quad * 4) = pb[i][j];
    }
    __syncthreads();                        // (B) Pbuf ready (cheap: no vmem pending)
    if (c < 7) {                            // prefetch V chunk c+1, covered by MFMAs
      const int nb = (c + 1) & 1;
#pragma unroll
      for (int p = 0; p < 4; p++) {
        const int s = p * 512 + tid;
        const int row = s >> 3, pc = s & 7;
        const int cc = pc ^ (row & 7);
        __builtin_amdgcn_global_load_lds(
            (AS1C)(Vb + (size_t)row * 512 + (c + 1) * 64 + cc * 8),
            (AS3P)(lds + nb * 16384 + s * 8), 16, 0, 0);
      }
    }
    const u16* Vc = lds + (c & 1) * 16384;
    __builtin_amdgcn_s_setprio(1);
#pragma unroll
    for (int ks = 0; ks < 2; ks++) {
      short8 ap[4];
#pragma unroll
      for (int i = 0; i < 4; i++)
        ap[i] = *(const short8*)(Pb + (i * 16 + ln) * 72 + ks * 32 + quad * 8);
#pragma unroll
      for (int j = 0; j < 2; j++) {
        const int kV = wno + j * 16 + ln;
        const short8 bv = *(const short8*)(Vc + kV * 64 + (((ks << 2) + quad) ^ (kV & 7)) * 8);
#pragma unroll
        for (int i = 0; i < 4; i++)
          o[i][j] = __builtin_amdgcn_mfma_f32_16x16x32_bf16(bv, ap[i], o[i][j], 0, 0, 0);
      }
    }
    __builtin_amdgcn_s_setprio(0);
  }

  // ---- epilogue: write CTX rows [bw*512+mt*64 .. +64), cols h*256+wno+.. ----
  const size_t tokr0 = (size_t)bw * 512 + mt * 64;
#pragma unroll
  for (int i = 0; i < 4; i++) {
    const size_t row = tokr0 + i * 16 + ln;
#pragma unroll
    for (int j = 0; j < 2; j++) {
      const int col = h * 256 + wno + j * 16 + quad * 4;
      ushort4 ob;
      ob.x = f2b(o[i][j][0]); ob.y = f2b(o[i][j][1]);
      ob.z = f2b(o[i][j][2]); ob.w = f2b(o[i][j][3]);
      *(ushort4*)(ctx + row * 512 + col) = ob;
    }
  }
}

// ---------------------------------------------------------------------------
// GEMM (N=256) + residual + LayerNorm (r7 ring-3 counted-vmcnt, UNCHANGED).
__global__ __launch_bounds__(256) void gemm_ln(
    const u16* __restrict__ A, const u16* __restrict__ BT,
    const float* __restrict__ bias, const u16* __restrict__ residb,
    const float* __restrict__ g, const float* __restrict__ beta,
    float* __restrict__ yout, u16* __restrict__ ybout, int K)
{
  __shared__ __align__(16) u16 ring[3][10240];   // 3 x 20KB: A[0..2048) B[2048..10240)
  __shared__ float redS[4][64], redQ[4][64];
  const int tid = threadIdx.x, lane = tid & 63, wid = tid >> 6;
  const int ln = lane & 15, quad = lane >> 4;
  const int qsw = (ln >> 1) & 3;
  const long bm = (long)blockIdx.x * 64;
  const int wn = wid * 64;
  const u16* Ab = A + (size_t)bm * K;
  const int nk = K >> 5;

  f32x4 acc[4][4];
#pragma unroll
  for (int i = 0; i < 4; i++)
#pragma unroll
    for (int j = 0; j < 4; j++) acc[i][j] = (f32x4){0.f, 0.f, 0.f, 0.f};

  // prologue: stage steps 0,1 -> ring 0,1 (5 loads/thread each)
#pragma unroll
  for (int sl = 0; sl < 2; sl++) {
    const int kt = sl * 32;
    const int row = tid >> 2;
    const int c = (tid & 3) ^ ((row >> 1) & 3);
    __builtin_amdgcn_global_load_lds(
        (AS1C)(Ab + (size_t)row * K + kt + c * 8), (AS3P)(&ring[sl][0] + tid * 8), 16, 0, 0);
#pragma unroll
    for (int p = 0; p < 4; p++) {
      const int s = p * 256 + tid;
      const int br = s >> 2;
      const int bc = (s & 3) ^ ((br >> 1) & 3);
      __builtin_amdgcn_global_load_lds(
          (AS1C)(BT + (size_t)br * K + kt + bc * 8), (AS3P)(&ring[sl][2048] + s * 8), 16, 0, 0);
    }
  }

  for (int kti = 0; kti < nk; kti++) {
    if (kti + 1 < nk) VMW(5); else VMW(0);
    SCHEDB();
    __builtin_amdgcn_s_barrier();
    SCHEDB();
    const u16* Rc = &ring[kti % 3][0];
    short8 a[4], b[4];
#pragma unroll
    for (int i = 0; i < 4; i++)
      a[i] = *(const short8*)(Rc + ((i * 16 + ln) * 4 + (quad ^ qsw)) * 8);
#pragma unroll
    for (int j = 0; j < 4; j++)
      b[j] = *(const short8*)(Rc + 2048 + ((wn + j * 16 + ln) * 4 + (quad ^ qsw)) * 8);
    __builtin_amdgcn_s_setprio(1);
#pragma unroll
    for (int i = 0; i < 4; i++)
#pragma unroll
      for (int j = 0; j < 4; j++)
        acc[i][j] = __builtin_amdgcn_mfma_f32_16x16x32_bf16(b[j], a[i], acc[i][j], 0, 0, 0);
    __builtin_amdgcn_s_setprio(0);
    // issue step kti+2 (ring[(kti+2)%3] last read iter kti-1; barrier separates)
    if (kti + 2 < nk) {
      const int kt = (kti + 2) * 32;
      u16* Rn = &ring[(kti + 2) % 3][0];
      const int row = tid >> 2;
      const int c = (tid & 3) ^ ((row >> 1) & 3);
      __builtin_amdgcn_global_load_lds(
          (AS1C)(Ab + (size_t)row * K + kt + c * 8), (AS3P)(Rn + tid * 8), 16, 0, 0);
#pragma unroll
      for (int p = 0; p < 4; p++) {
        const int s = p * 256 + tid;
        const int br = s >> 2;
        const int bc = (s & 3) ^ ((br >> 1) & 3);
        __builtin_amdgcn_global_load_lds(
            (AS1C)(BT + (size_t)br * K + kt + bc * 8), (AS3P)(Rn + 2048 + s * 8), 16, 0, 0);
      }
    }
  }

  // ---- epilogue: v = acc + bias + resid; LayerNorm over the 256-row ----
#pragma unroll
  for (int i = 0; i < 4; i++) {
    const long gm = bm + i * 16 + ln;
    float s = 0.f, q = 0.f;
#pragma unroll
    for (int j = 0; j < 4; j++) {
      const int n0 = wn + j * 16 + quad * 4;
      const float4 b4 = *(const float4*)(bias + n0);
      const ushort4 r4 = *(const ushort4*)(residb + (size_t)gm * 256 + n0);
      acc[i][j][0] += b4.x + b2f(r4.x);
      acc[i][j][1] += b4.y + b2f(r4.y);
      acc[i][j][2] += b4.z + b2f(r4.z);
      acc[i][j][3] += b4.w + b2f(r4.w);
#pragma unroll
      for (int r = 0; r < 4; r++) { s += acc[i][j][r]; q += acc[i][j][r] * acc[i][j][r]; }
    }
    s += __shfl_xor(s, 16); s += __shfl_xor(s, 32);
    q += __shfl_xor(q, 16); q += __shfl_xor(q, 32);
    if (quad == 0) { redS[wid][i * 16 + ln] = s; redQ[wid][i * 16 + ln] = q; }
  }
  __syncthreads();
#pragma unroll
  for (int i = 0; i < 4; i++) {
    const long gm = bm + i * 16 + ln;
    float s = 0.f, q = 0.f;
#pragma unroll
    for (int w = 0; w < 4; w++) { s += redS[w][i * 16 + ln]; q += redQ[w][i * 16 + ln]; }
    const float mu = s * (1.f / 256.f);
    const float inv = rsqrtf(q * (1.f / 256.f) - mu * mu + 1e-3f);
#pragma unroll
    for (int j = 0; j < 4; j++) {
      const int n0 = wn + j * 16 + quad * 4;
      const float4 gg = *(const float4*)(g + n0);
      const float4 bb = *(const float4*)(beta + n0);
      float o0 = (acc[i][j][0] - mu) * inv * gg.x + bb.x;
      float o1 = (acc[i][j][1] - mu) * inv * gg.y + bb.y;
      float o2 = (acc[i][j][2] - mu) * inv * gg.z + bb.z;
      float o3 = (acc[i][j][3] - mu) * inv * gg.w + bb.w;
      const size_t off = (size_t)gm * 256 + n0;
      if (yout) {
        float4 o4; o4.x = o0; o4.y = o1; o4.z = o2; o4.w = o3;
        *(float4*)(yout + off) = o4;
      }
      if (ybout) {
        ushort4 ob;
        ob.x = f2b(o0); ob.y = f2b(o1); ob.z = f2b(o2); ob.w = f2b(o3);
        *(ushort4*)(ybout + off) = ob;
      }
    }
  }
}

// ---------------------------------------------------------------------------
extern "C" void kernel_launch(void* const* d_in, const int* in_sizes, int n_in,
                              void* d_out, int out_size, void* d_ws, size_t ws_size,
                              hipStream_t stream) {
  (void)in_sizes; (void)n_in; (void)out_size; (void)ws_size;
  const float* x    = (const float*)d_in[0];
  const float* Wq   = (const float*)d_in[1];
  const float* bq   = (const float*)d_in[2];
  const float* Wk   = (const float*)d_in[3];
  const float* bk   = (const float*)d_in[4];
  const float* Wv   = (const float*)d_in[5];
  const float* bv   = (const float*)d_in[6];
  const float* Wo   = (const float*)d_in[7];
  const float* bo   = (const float*)d_in[8];
  const float* ln1g = (const float*)d_in[9];
  const float* ln1b = (const float*)d_in[10];
  const float* W1   = (const float*)d_in[11];
  const float* b1   = (const float*)d_in[12];
  const float* W2   = (const float*)d_in[13];
  const float* b2   = (const float*)d_in[14];
  const float* ln2g = (const float*)d_in[15];
  const float* ln2b = (const float*)d_in[16];
  float* out = (float*)d_out;

  char* ws = (char*)d_ws;
  u16*   WQKVT = (u16*)(ws + OFF_WQKVT);
  u16*   WOT   = (u16*)(ws + OFF_WOT);
  u16*   W1T   = (u16*)(ws + OFF_W1T);
  u16*   W2T   = (u16*)(ws + OFF_W2T);
  float* BQKV  = (float*)(ws + OFF_BQKV);
  u16*   XB    = (u16*)(ws + OFF_XB);
  u16*   QKV   = (u16*)(ws + OFF_QKV);
  u16*   YB    = (u16*)(ws + OFF_YB);
  u16*   HB    = (u16*)(ws + OFF_HB);
  u16*   VT    = (u16*)(ws + OFF_VT);
  u16*   CTX   = (u16*)(ws + OFF_CTX);

  cast_x_kernel<<<8192, 256, 0, stream>>>(x, XB);
  prep_w_kernel<<<257, 256, 0, stream>>>(Wq, Wk, Wv, Wo, W1, W2, bq, bk, bv,
                                         WQKVT, WOT, W1T, W2T, BQKV);
  // QKV projection (128-col panels, 512-row m-chunks): Q,K -> QKV; V -> VT
  gemm_nres<<<768, 256, 0, stream>>>(XB, WQKVT, BQKV, QKV, VT, 1536, 1024, 0);
  // Fused attention v6 (unchanged)
  attn_fused<<<1024, 512, 0, stream>>>(QKV, VT, CTX);
  // attn-out projection + residual(XB) + LN1 -> YB (bf16)
  gemm_ln<<<512, 256, 0, stream>>>(CTX, WOT, bo, XB, ln1g, ln1b, nullptr, YB, 512);
  // FF1 + ReLU (128-col panels): [32768,256] x [256,1024]
  gemm_nres<<<512, 256, 0, stream>>>(YB, W1T, b1, HB, nullptr, 1024, 1 << 30, 1);
  // FF2 + residual(YB) + LN2 -> out (f32)
  gemm_ln<<<512, 256, 0, stream>>>(HB, W2T, b2, YB, ln2g, ln2b, out, nullptr, 1024);
}